// Round 11
// baseline (533.625 us; speedup 1.0000x reference)
//
#include <hip/hip_runtime.h>

#define RR 3
#define NN 50000
#define EE 800000
#define FF 128
#define DD 128
#define AA 64
#define EPSF 1e-5f
#define RN (RR * NN)
#define RE (RR * EE)
#define NTPR ((NN + 127) / 128)     // 391 dst-tiles (128 nodes) per relation
#define NBK (RR * NTPR)             // 1173 buckets
#define ECHUNK 8192                 // edges per bucketing block
#define NEBLK ((RE + ECHUNK - 1) / ECHUNK)   // 293
#define NTILES (NN / 16)            // 3125 exact

typedef __attribute__((ext_vector_type(8))) short bf16x8;
typedef __attribute__((ext_vector_type(4))) float f32x4;
typedef __attribute__((ext_vector_type(4))) unsigned int u32x4;

__device__ __forceinline__ short f2bs(float x) {
    union { float f; unsigned u; } v; v.f = x;
    unsigned rr = (v.u + 0x7fffu + ((v.u >> 16) & 1u)) >> 16;  // RNE
    return (short)(rr & 0xffffu);
}

__device__ __forceinline__ unsigned pk2(float a, float b) {  // bf16(a) lo | bf16(b) hi
    return ((unsigned)(unsigned short)f2bs(b) << 16) | (unsigned)(unsigned short)f2bs(a);
}

__device__ __forceinline__ float bs2f_lo(int p) {
    union { unsigned u; float f; } v; v.u = (unsigned)p << 16; return v.f;
}
__device__ __forceinline__ float bs2f_hi(int p) {
    union { unsigned u; float f; } v; v.u = (unsigned)p & 0xffff0000u; return v.f;
}

__device__ __forceinline__ int rel_of(long e) {
    return (e >= 2L * EE) ? 2 : ((e >= (long)EE) ? 1 : 0);
}

__device__ __forceinline__ float ftanh(float x) {   // overflow-safe fast tanh
    float a = __expf(2.0f * fabsf(x));
    return copysignf(1.0f - 2.0f / (a + 1.0f), x);
}

// ---------------- feat -> bf16 ----------------
__global__ __launch_bounds__(256)
void feat2bf16(const float* __restrict__ feat, short* __restrict__ featb) {
    int gid = blockIdx.x * blockDim.x + threadIdx.x;
    if (gid >= NN * 16) return;
    f32x4 a = ((const f32x4*)feat)[2 * gid];
    f32x4 b = ((const f32x4*)feat)[2 * gid + 1];
    bf16x8 o;
    o[0] = f2bs(a.x); o[1] = f2bs(a.y); o[2] = f2bs(a.z); o[3] = f2bs(a.w);
    o[4] = f2bs(b.x); o[5] = f2bs(b.y); o[6] = f2bs(b.z); o[7] = f2bs(b.w);
    ((bf16x8*)featb)[gid] = o;
}

// ------- count: per-node degree (global) + bucket histogram (LDS-aggregated) -------
__global__ __launch_bounds__(256)
void count_kernel(const int* __restrict__ dst, int* __restrict__ cnt,
                  int* __restrict__ bcnt) {
    __shared__ int hist[NBK];
    for (int i = threadIdx.x; i < NBK; i += 256) hist[i] = 0;
    __syncthreads();
    long ebase = (long)blockIdx.x * ECHUNK;
    for (int i = threadIdx.x; i < ECHUNK; i += 256) {
        long e = ebase + i;
        if (e < RE) {
            int r = rel_of(e);
            int d = dst[e];
            atomicAdd(&cnt[r * NN + d], 1);
            atomicAdd(&hist[r * NTPR + (d >> 7)], 1);
        }
    }
    __syncthreads();
    for (int i = threadIdx.x; i < NBK; i += 256) {
        int v = hist[i];
        if (v) atomicAdd(&bcnt[i], v);   // no-return, spread
    }
}

// ---------------- node-offset scan (3-phase over RN) -> START offsets ----------------
__global__ __launch_bounds__(256)
void scan_phase1(const int* __restrict__ cnt, int* __restrict__ bsum) {
    __shared__ int sm[4];
    int b = blockIdx.x, t = threadIdx.x;
    int base = b * 1024 + t * 4;
    int s = 0;
    if (base + 3 < RN) {
        int4 v = *(const int4*)(cnt + base);
        s = v.x + v.y + v.z + v.w;
    } else {
        for (int i = 0; i < 4; ++i) if (base + i < RN) s += cnt[base + i];
    }
    #pragma unroll
    for (int m = 1; m < 64; m <<= 1) s += __shfl_xor(s, m);
    if ((t & 63) == 0) sm[t >> 6] = s;
    __syncthreads();
    if (t == 0) bsum[b] = sm[0] + sm[1] + sm[2] + sm[3];
}

__global__ __launch_bounds__(256)
void scan_phase2(int* __restrict__ bsum, int nb) {   // single block
    __shared__ int sm[256];
    int t = threadIdx.x;
    int v = (t < nb) ? bsum[t] : 0;
    sm[t] = v;
    __syncthreads();
    for (int d = 1; d < 256; d <<= 1) {
        int u = (t >= d) ? sm[t - d] : 0;
        __syncthreads();
        sm[t] += u;
        __syncthreads();
    }
    if (t < nb) bsum[t] = sm[t] - v;   // exclusive
}

__global__ __launch_bounds__(256)
void scan_phase3(const int* __restrict__ cnt, const int* __restrict__ bsum,
                 int* __restrict__ off) {
    __shared__ int sm[256];
    int b = blockIdx.x, t = threadIdx.x;
    int base = b * 1024 + t * 4;
    int c0 = 0, c1 = 0, c2 = 0, c3 = 0;
    if (base + 3 < RN) {
        int4 v = *(const int4*)(cnt + base);
        c0 = v.x; c1 = v.y; c2 = v.z; c3 = v.w;
    } else {
        if (base + 0 < RN) c0 = cnt[base + 0];
        if (base + 1 < RN) c1 = cnt[base + 1];
        if (base + 2 < RN) c2 = cnt[base + 2];
        if (base + 3 < RN) c3 = cnt[base + 3];
    }
    int s = c0 + c1 + c2 + c3;
    sm[t] = s;
    __syncthreads();
    for (int d = 1; d < 256; d <<= 1) {
        int u = (t >= d) ? sm[t - d] : 0;
        __syncthreads();
        sm[t] += u;
        __syncthreads();
    }
    int pre = bsum[b] + sm[t] - s;
    if (base + 0 < RN) off[base + 0] = pre;
    if (base + 1 < RN) off[base + 1] = pre + c0;
    if (base + 2 < RN) off[base + 2] = pre + c0 + c1;
    if (base + 3 < RN) off[base + 3] = pre + c0 + c1 + c2;
}

// ---------------- bucket scan (1173 buckets, single block) ----------------
__global__ __launch_bounds__(256)
void bscan_kernel(const int* __restrict__ bcnt, int* __restrict__ bstart,
                  int* __restrict__ boff) {
    __shared__ int sm[256];
    int t = threadIdx.x;
    int loc[5];
    int s = 0;
    #pragma unroll
    for (int i = 0; i < 5; ++i) {
        int idx = t * 5 + i;
        int v = (idx < NBK) ? bcnt[idx] : 0;
        loc[i] = v; s += v;
    }
    sm[t] = s;
    __syncthreads();
    for (int d = 1; d < 256; d <<= 1) {
        int u = (t >= d) ? sm[t - d] : 0;
        __syncthreads();
        sm[t] += u;
        __syncthreads();
    }
    int run = sm[t] - s;   // exclusive prefix
    #pragma unroll
    for (int i = 0; i < 5; ++i) {
        int idx = t * 5 + i;
        if (idx < NBK) { bstart[idx] = run; boff[idx] = run; run += loc[i]; }
    }
}

// ------- phase A: block-aggregated bucket scatter (LDS hist + range reservation) -------
__global__ __launch_bounds__(256)
void bscatterA(const int* __restrict__ src, const int* __restrict__ dst,
               int* __restrict__ boff, unsigned* __restrict__ bpair) {
    __shared__ int hist[NBK];
    __shared__ int base[NBK];
    for (int i = threadIdx.x; i < NBK; i += 256) hist[i] = 0;
    __syncthreads();
    long ebase = (long)blockIdx.x * ECHUNK;
    for (int i = threadIdx.x; i < ECHUNK; i += 256) {
        long e = ebase + i;
        if (e < RE)
            atomicAdd(&hist[rel_of(e) * NTPR + (dst[e] >> 7)], 1);
    }
    __syncthreads();
    for (int i = threadIdx.x; i < NBK; i += 256) {
        int v = hist[i];
        base[i] = v ? atomicAdd(&boff[i], v) : 0;   // one reservation per (block,bucket)
    }
    __syncthreads();
    for (int i = threadIdx.x; i < ECHUNK; i += 256) {
        long e = ebase + i;
        if (e < RE) {
            int r = rel_of(e);
            int d = dst[e];
            int b = r * NTPR + (d >> 7);
            int pos = atomicAdd(&base[b], 1);       // LDS cursor bump
            bpair[pos] = ((unsigned)(d & 127) << 16) | (unsigned)src[e];
        }
    }
}

// ------- phase B: per-bucket local scatter, zero global atomics -------
__global__ __launch_bounds__(256)
void scatterB(const unsigned* __restrict__ bpair, const int* __restrict__ bstart,
              const int* __restrict__ bcnt, const int* __restrict__ off,
              int* __restrict__ csr) {
    __shared__ int nb[128], cur[128];
    int b = blockIdx.x;
    int r = b / NTPR, tile = b - r * NTPR;
    if (threadIdx.x < 128) {
        int nloc = tile * 128 + threadIdx.x;
        nb[threadIdx.x] = (nloc < NN) ? off[r * NN + nloc] : 0;
        cur[threadIdx.x] = 0;
    }
    __syncthreads();
    int start = bstart[b], end = start + bcnt[b];
    for (int i = start + threadIdx.x; i < end; i += 256) {
        unsigned p = bpair[i];
        int d = (int)(p >> 16);
        int rank = atomicAdd(&cur[d], 1);           // LDS only
        csr[nb[d] + rank] = (int)(p & 0xFFFFu);
    }
}

// ------- aggregation: wave per (r,node), 4-way ILP-unrolled bf16 gather -------
__global__ __launch_bounds__(256)
void gather_kernel(const short* __restrict__ featb,
                   const int* __restrict__ csr,
                   const int* __restrict__ off,   // START offsets (never mutated)
                   const int* __restrict__ cnt,
                   short* __restrict__ ssumb) {   // [R][N][F] <- bf16(feat + mean)
    int gid = blockIdx.x * blockDim.x + threadIdx.x;
    int w = gid >> 6, lane = gid & 63;
    if (w >= RN) return;
    int c = cnt[w];
    int start = off[w];
    int end = start + c;
    const int* f2 = (const int*)featb;
    float ax0 = 0.f, ay0 = 0.f, ax1 = 0.f, ay1 = 0.f;
    float ax2 = 0.f, ay2 = 0.f, ax3 = 0.f, ay3 = 0.f;
    int j = start;
    for (; j + 3 < end; j += 4) {
        int s0 = csr[j + 0];
        int s1 = csr[j + 1];
        int s2 = csr[j + 2];
        int s3 = csr[j + 3];
        int v0 = f2[(size_t)s0 * 64 + lane];
        int v1 = f2[(size_t)s1 * 64 + lane];
        int v2 = f2[(size_t)s2 * 64 + lane];
        int v3 = f2[(size_t)s3 * 64 + lane];
        ax0 += bs2f_lo(v0); ay0 += bs2f_hi(v0);
        ax1 += bs2f_lo(v1); ay1 += bs2f_hi(v1);
        ax2 += bs2f_lo(v2); ay2 += bs2f_hi(v2);
        ax3 += bs2f_lo(v3); ay3 += bs2f_hi(v3);
    }
    for (; j < end; ++j) {
        int s = csr[j];
        int v = f2[(size_t)s * 64 + lane];
        ax0 += bs2f_lo(v); ay0 += bs2f_hi(v);
    }
    float ax = (ax0 + ax1) + (ax2 + ax3);
    float ay = (ay0 + ay1) + (ay2 + ay3);
    float inv = 1.0f / fmaxf((float)c, 1.0f);
    int n = w % NN;
    int fv = f2[(size_t)n * 64 + lane];
    float hx = bs2f_lo(fv) + ax * inv;
    float hy = bs2f_hi(fv) + ay * inv;
    unsigned plo = (unsigned short)f2bs(hx);
    unsigned phi = (unsigned short)f2bs(hy);
    ((int*)ssumb)[(size_t)w * 64 + lane] = (int)((phi << 16) | plo);
}

// ======== transposed-operand fused transform: X^T = W^T · h^T, no ht LDS ========
// C-layout per m89: row = (lane>>4)*4 + q, col = lane&15. Here row=d, col=n.

template <bool RELU, bool BIAS>
__device__ __forceinline__ void ln_t(f32x4 acc[8], const float* bias,
                                     const float* gam, const float* bet, int g4) {
    float s = 0.f, p = 0.f;
    #pragma unroll
    for (int t = 0; t < 8; ++t) {
        if (BIAS) {
            f32x4 bv = *(const f32x4*)&bias[t * 16 + g4];
            acc[t] += bv;
        }
        s += acc[t][0] + acc[t][1] + acc[t][2] + acc[t][3];
        p += acc[t][0] * acc[t][0] + acc[t][1] * acc[t][1]
           + acc[t][2] * acc[t][2] + acc[t][3] * acc[t][3];
    }
    s += __shfl_xor(s, 16); p += __shfl_xor(p, 16);
    s += __shfl_xor(s, 32); p += __shfl_xor(p, 32);
    const float inv = 1.0f / 128.0f;
    float mu = s * inv;
    float rstd = rsqrtf(p * inv - mu * mu + EPSF);
    #pragma unroll
    for (int t = 0; t < 8; ++t) {
        f32x4 gv = *(const f32x4*)&gam[t * 16 + g4];
        f32x4 bv = *(const f32x4*)&bet[t * 16 + g4];
        f32x4 v = (acc[t] - mu) * rstd * gv + bv;
        if (RELU) {
            v[0] = fmaxf(v[0], 0.f); v[1] = fmaxf(v[1], 0.f);
            v[2] = fmaxf(v[2], 0.f); v[3] = fmaxf(v[3], 0.f);
        }
        acc[t] = v;
    }
}

__global__ __launch_bounds__(512)
void fused_transform2(short* hbuf,                // ssumb in, h (bf16) out, in-place
                      const float* __restrict__ W0, const float* __restrict__ b0,
                      const float* __restrict__ W1, const float* __restrict__ b1,
                      const float* __restrict__ ln_g, const float* __restrict__ ln_b,
                      const float* __restrict__ LN_g, const float* __restrict__ LN_b) {
    __shared__ short W0t[FF * DD];        // 32 KiB, [d_out][k] bf16, XOR-swizzled
    __shared__ short W1t[DD * DD];        // 32 KiB
    __shared__ float b0s[DD], b1s[DD], lgs[DD], lbs[DD], Lgs[DD], Lbs[DD];

    const int r = blockIdx.y;
    const int tid = threadIdx.x;

    for (int i = tid; i < FF * DD; i += 512) {
        int k = i >> 7, d = i & 127;                 // global read coalesced over d
        int idx = d * 128 + (k ^ ((d & 7) << 3));
        W0t[idx] = f2bs(W0[(size_t)r * FF * DD + i]);
        W1t[idx] = f2bs(W1[(size_t)r * DD * DD + i]);
    }
    if (tid < DD) {
        b0s[tid] = b0[r * DD + tid];
        b1s[tid] = b1[r * DD + tid];
        lgs[tid] = ln_g[r * DD + tid];
        lbs[tid] = ln_b[r * DD + tid];
        Lgs[tid] = LN_g[tid];
        Lbs[tid] = LN_b[tid];
    }
    __syncthreads();   // only barrier; no syncs in the tile loop

    const int wv = tid >> 6, ln = tid & 63;
    const int col = ln & 15, g = ln >> 4;
    const int g8 = g * 8, g4 = g * 4;
    const int hi = g >> 1;                            // selects t = 2kk + hi
    const int sA = ((g & 1) << 5) + col;              // source lane for j=0..3
    const int sB = sA + 16;                           // source lane for j=4..7

    for (int tile = blockIdx.x * 8 + wv; tile < NTILES; tile += gridDim.x * 8) {
        const int nbase = tile * 16;
        short* hrow = hbuf + ((size_t)r * NN + nbase + col) * FF;

        // B1 = h^T fragments straight from global (lane col = node)
        bf16x8 B[4];
        #pragma unroll
        for (int kk = 0; kk < 4; ++kk)
            B[kk] = *(const bf16x8*)(hrow + kk * 32 + g8);

        // layer 1: acc[t] = W0_tile(t) · h^T
        f32x4 acc[8];
        #pragma unroll
        for (int t = 0; t < 8; ++t) acc[t] = (f32x4){0.f, 0.f, 0.f, 0.f};
        #pragma unroll
        for (int kk = 0; kk < 4; ++kk)
            #pragma unroll
            for (int t = 0; t < 8; ++t) {
                int d = t * 16 + col;
                bf16x8 Wf = *(const bf16x8*)&W0t[d * 128 + ((kk * 32 + g8) ^ ((d & 7) << 3))];
                acc[t] = __builtin_amdgcn_mfma_f32_16x16x32_bf16(Wf, B[kk], acc[t], 0, 0, 0);
            }
        ln_t<true, true>(acc, b0s, lgs, lbs, g4);

        // rebuild B2 (X1^T fragments) via in-register shuffles within column group
        {
            unsigned p0[8], p1[8];
            #pragma unroll
            for (int t = 0; t < 8; ++t) {
                p0[t] = pk2(acc[t][0], acc[t][1]);
                p1[t] = pk2(acc[t][2], acc[t][3]);
            }
            #pragma unroll
            for (int kk = 0; kk < 4; ++kk) {
                int ta = 2 * kk, tb = 2 * kk + 1;
                unsigned a0 = __shfl((int)p0[ta], sA), c0 = __shfl((int)p0[tb], sA);
                unsigned a1 = __shfl((int)p1[ta], sA), c1 = __shfl((int)p1[tb], sA);
                unsigned a2 = __shfl((int)p0[ta], sB), c2 = __shfl((int)p0[tb], sB);
                unsigned a3 = __shfl((int)p1[ta], sB), c3 = __shfl((int)p1[tb], sB);
                union { u32x4 u; bf16x8 v; } uu;
                uu.u = (u32x4){hi ? c0 : a0, hi ? c1 : a1, hi ? c2 : a2, hi ? c3 : a3};
                B[kk] = uu.v;
            }
        }

        // layer 2
        #pragma unroll
        for (int t = 0; t < 8; ++t) acc[t] = (f32x4){0.f, 0.f, 0.f, 0.f};
        #pragma unroll
        for (int kk = 0; kk < 4; ++kk)
            #pragma unroll
            for (int t = 0; t < 8; ++t) {
                int d = t * 16 + col;
                bf16x8 Wf = *(const bf16x8*)&W1t[d * 128 + ((kk * 32 + g8) ^ ((d & 7) << 3))];
                acc[t] = __builtin_amdgcn_mfma_f32_16x16x32_bf16(Wf, B[kk], acc[t], 0, 0, 0);
            }
        ln_t<true, true>(acc, b1s, lgs, lbs, g4);
        ln_t<false, false>(acc, nullptr, Lgs, Lbs, g4);   // final LayerNorm

        // write h (bf16) back: lane writes 8B per t at h[n=col][d = t*16+g*4 ..+3]
        #pragma unroll
        for (int t = 0; t < 8; ++t) {
            uint2 w;
            w.x = pk2(acc[t][0], acc[t][1]);
            w.y = pk2(acc[t][2], acc[t][3]);
            *(uint2*)&hrow[t * 16 + g4] = w;
        }
    }
}

// ---------- attention scores: e = tanh(h @ Wa1) . Wa2 (transposed mfma) ----------
__global__ __launch_bounds__(256)
void attn_score(const short* __restrict__ hbuf,
                const float* __restrict__ Wa1, const float* __restrict__ Wa2,
                float* __restrict__ evec) {
    __shared__ short Wa1t[RR][AA * DD];   // 48 KiB, [r][a][k] swizzled
    __shared__ float wa2s[RR][AA];

    const int tid = threadIdx.x;
    for (int i = tid; i < RR * DD * AA; i += 256) {
        int r2 = i >> 13;                  // / 8192
        int rem = i & 8191;
        int k = rem >> 6, a = rem & 63;
        Wa1t[r2][a * 128 + (k ^ ((a & 7) << 3))] = f2bs(Wa1[i]);
    }
    if (tid < RR * AA) wa2s[tid >> 6][tid & 63] = Wa2[tid];
    __syncthreads();

    const int wv = tid >> 6, ln = tid & 63;
    const int col = ln & 15, g = ln >> 4;
    const int g8 = g * 8, g4 = g * 4;

    for (int idx = blockIdx.x * 4 + wv; idx < RR * NTILES; idx += gridDim.x * 4) {
        int r = idx / NTILES;
        int tile = idx - r * NTILES;
        int nbase = tile * 16;
        const short* hrow = hbuf + ((size_t)r * NN + nbase + col) * FF;

        f32x4 acc[4];
        #pragma unroll
        for (int t = 0; t < 4; ++t) acc[t] = (f32x4){0.f, 0.f, 0.f, 0.f};
        #pragma unroll
        for (int kk = 0; kk < 4; ++kk) {
            bf16x8 Bh = *(const bf16x8*)(hrow + kk * 32 + g8);
            #pragma unroll
            for (int t = 0; t < 4; ++t) {
                int a_ = t * 16 + col;
                bf16x8 Wf = *(const bf16x8*)&Wa1t[r][a_ * 128 + ((kk * 32 + g8) ^ ((a_ & 7) << 3))];
                acc[t] = __builtin_amdgcn_mfma_f32_16x16x32_bf16(Wf, Bh, acc[t], 0, 0, 0);
            }
        }
        float e = 0.f;
        #pragma unroll
        for (int t = 0; t < 4; ++t) {
            f32x4 wv2 = *(const f32x4*)&wa2s[r][t * 16 + g4];
            e += ftanh(acc[t][0]) * wv2[0] + ftanh(acc[t][1]) * wv2[1]
               + ftanh(acc[t][2]) * wv2[2] + ftanh(acc[t][3]) * wv2[3];
        }
        e += __shfl_xor(e, 16);
        e += __shfl_xor(e, 32);
        if (ln < 16) evec[(size_t)r * NN + nbase + ln] = e;
    }
}

// ---------------- softmax over relations + weighted combine ----------------
__global__ __launch_bounds__(256)
void combine_kernel(const short* __restrict__ hfb,
                    const float* __restrict__ evec,
                    float* __restrict__ out) {
    int gid = blockIdx.x * blockDim.x + threadIdx.x;
    if (gid >= NN * 64) return;
    int n = gid >> 6, j = gid & 63;
    float e0 = evec[n], e1 = evec[NN + n], e2 = evec[2 * NN + n];
    float m = fmaxf(e0, fmaxf(e1, e2));
    float w0 = __expf(e0 - m), w1 = __expf(e1 - m), w2 = __expf(e2 - m);
    float inv = 1.0f / (w0 + w1 + w2);
    w0 *= inv; w1 *= inv; w2 *= inv;
    const int* h0 = (const int*)hfb + (size_t)n * 64;
    const int* h1 = (const int*)hfb + ((size_t)NN + n) * 64;
    const int* h2 = (const int*)hfb + ((size_t)2 * NN + n) * 64;
    int a = h0[j], b = h1[j], d = h2[j];
    float2 o;
    o.x = w0 * bs2f_lo(a) + w1 * bs2f_lo(b) + w2 * bs2f_lo(d);
    o.y = w0 * bs2f_hi(a) + w1 * bs2f_hi(b) + w2 * bs2f_hi(d);
    ((float2*)out)[(size_t)n * 64 + j] = o;
}

extern "C" void kernel_launch(void* const* d_in, const int* in_sizes, int n_in,
                              void* d_out, int out_size, void* d_ws, size_t ws_size,
                              hipStream_t stream) {
    const float* feat = (const float*)d_in[0];
    const int*   src  = (const int*)d_in[1];
    const int*   dst  = (const int*)d_in[2];
    const float* W0   = (const float*)d_in[3];
    const float* b0   = (const float*)d_in[4];
    const float* W1   = (const float*)d_in[5];
    const float* b1   = (const float*)d_in[6];
    const float* ln_g = (const float*)d_in[7];
    const float* ln_b = (const float*)d_in[8];
    const float* LN_g = (const float*)d_in[9];
    const float* LN_b = (const float*)d_in[10];
    const float* Wa1  = (const float*)d_in[11];
    const float* Wa2  = (const float*)d_in[12];
    float* out = (float*)d_out;

    // workspace layout
    short*    ssumb  = (short*)d_ws;                        // RN*FF bf16 (38.4 MB)
    short*    featb  = ssumb + (size_t)RN * FF;             // NN*FF bf16 (12.8 MB)
    int*      cnt    = (int*)(featb + (size_t)NN * FF);     // RN
    int*      off    = cnt + RN;                            // RN (start offsets)
    int*      csr    = off + RN;                            // RE
    float*    evec   = (float*)(csr + RE);                  // RN
    int*      bsum   = (int*)(evec + RN);                   // 256
    int*      bcnt   = bsum + 256;                          // NBK
    int*      bstart = bcnt + NBK;                          // NBK
    int*      boff   = bstart + NBK;                        // NBK
    unsigned* bpair  = (unsigned*)(boff + NBK);             // RE (9.6 MB)

    const int NB = (RN + 1023) / 1024;                      // 147

    feat2bf16<<<(NN * 16 + 255) / 256, 256, 0, stream>>>(feat, featb);
    hipMemsetAsync(cnt, 0, (size_t)RN * sizeof(int), stream);
    hipMemsetAsync(bcnt, 0, (size_t)NBK * sizeof(int), stream);
    count_kernel<<<NEBLK, 256, 0, stream>>>(dst, cnt, bcnt);
    scan_phase1<<<NB, 256, 0, stream>>>(cnt, bsum);
    scan_phase2<<<1, 256, 0, stream>>>(bsum, NB);
    scan_phase3<<<NB, 256, 0, stream>>>(cnt, bsum, off);
    bscan_kernel<<<1, 256, 0, stream>>>(bcnt, bstart, boff);
    bscatterA<<<NEBLK, 256, 0, stream>>>(src, dst, boff, bpair);
    scatterB<<<NBK, 256, 0, stream>>>(bpair, bstart, bcnt, off, csr);
    gather_kernel<<<(RN * 64 + 255) / 256, 256, 0, stream>>>(featb, csr, off, cnt, ssumb);

    fused_transform2<<<dim3(170, RR), 512, 0, stream>>>(
        ssumb, W0, b0, W1, b1, ln_g, ln_b, LN_g, LN_b);
    attn_score<<<512, 256, 0, stream>>>(ssumb, Wa1, Wa2, evec);
    combine_kernel<<<(NN * 64 + 255) / 256, 256, 0, stream>>>(ssumb, evec, out);
}

// Round 12
// 476.556 us; speedup vs baseline: 1.1198x; 1.1198x over previous
//
#include <hip/hip_runtime.h>

#define RR 3
#define NN 50000
#define EE 800000
#define FF 128
#define DD 128
#define AA 64
#define EPSF 1e-5f
#define RN (RR * NN)
#define RE (RR * EE)
#define NTPR ((NN + 127) / 128)     // 391 dst-tiles (128 nodes) per relation
#define NBK (RR * NTPR)             // 1173 buckets
#define ECHUNK 8192                 // edges per bucketing block
#define NEBLK ((RE + ECHUNK - 1) / ECHUNK)   // 293

typedef __attribute__((ext_vector_type(8))) short bf16x8;
typedef __attribute__((ext_vector_type(4))) float f32x4;

__device__ __forceinline__ short f2bs(float x) {
    union { float f; unsigned u; } v; v.f = x;
    unsigned rr = (v.u + 0x7fffu + ((v.u >> 16) & 1u)) >> 16;  // RNE
    return (short)(rr & 0xffffu);
}

__device__ __forceinline__ float bs2f_lo(int p) {
    union { unsigned u; float f; } v; v.u = (unsigned)p << 16; return v.f;
}
__device__ __forceinline__ float bs2f_hi(int p) {
    union { unsigned u; float f; } v; v.u = (unsigned)p & 0xffff0000u; return v.f;
}

__device__ __forceinline__ int rel_of(long e) {
    return (e >= 2L * EE) ? 2 : ((e >= (long)EE) ? 1 : 0);
}

__device__ __forceinline__ float ftanh(float x) {   // overflow-safe fast tanh
    float a = __expf(2.0f * fabsf(x));
    return copysignf(1.0f - 2.0f / (a + 1.0f), x);
}

// ---------------- feat -> bf16 ----------------
__global__ __launch_bounds__(256)
void feat2bf16(const float* __restrict__ feat, short* __restrict__ featb) {
    int gid = blockIdx.x * blockDim.x + threadIdx.x;
    if (gid >= NN * 16) return;
    f32x4 a = ((const f32x4*)feat)[2 * gid];
    f32x4 b = ((const f32x4*)feat)[2 * gid + 1];
    bf16x8 o;
    o[0] = f2bs(a.x); o[1] = f2bs(a.y); o[2] = f2bs(a.z); o[3] = f2bs(a.w);
    o[4] = f2bs(b.x); o[5] = f2bs(b.y); o[6] = f2bs(b.z); o[7] = f2bs(b.w);
    ((bf16x8*)featb)[gid] = o;
}

// ------- count: per-node degree (global) + bucket histogram (LDS-aggregated) -------
__global__ __launch_bounds__(256)
void count_kernel(const int* __restrict__ dst, int* __restrict__ cnt,
                  int* __restrict__ bcnt) {
    __shared__ int hist[NBK];
    for (int i = threadIdx.x; i < NBK; i += 256) hist[i] = 0;
    __syncthreads();
    long ebase = (long)blockIdx.x * ECHUNK;
    for (int i = threadIdx.x; i < ECHUNK; i += 256) {
        long e = ebase + i;
        if (e < RE) {
            int r = rel_of(e);
            int d = dst[e];
            atomicAdd(&cnt[r * NN + d], 1);
            atomicAdd(&hist[r * NTPR + (d >> 7)], 1);
        }
    }
    __syncthreads();
    for (int i = threadIdx.x; i < NBK; i += 256) {
        int v = hist[i];
        if (v) atomicAdd(&bcnt[i], v);   // no-return, spread
    }
}

// ---------------- node-offset scan (3-phase over RN) -> START offsets ----------------
__global__ __launch_bounds__(256)
void scan_phase1(const int* __restrict__ cnt, int* __restrict__ bsum) {
    __shared__ int sm[4];
    int b = blockIdx.x, t = threadIdx.x;
    int base = b * 1024 + t * 4;
    int s = 0;
    if (base + 3 < RN) {
        int4 v = *(const int4*)(cnt + base);
        s = v.x + v.y + v.z + v.w;
    } else {
        for (int i = 0; i < 4; ++i) if (base + i < RN) s += cnt[base + i];
    }
    #pragma unroll
    for (int m = 1; m < 64; m <<= 1) s += __shfl_xor(s, m);
    if ((t & 63) == 0) sm[t >> 6] = s;
    __syncthreads();
    if (t == 0) bsum[b] = sm[0] + sm[1] + sm[2] + sm[3];
}

__global__ __launch_bounds__(256)
void scan_phase2(int* __restrict__ bsum, int nb) {   // single block
    __shared__ int sm[256];
    int t = threadIdx.x;
    int v = (t < nb) ? bsum[t] : 0;
    sm[t] = v;
    __syncthreads();
    for (int d = 1; d < 256; d <<= 1) {
        int u = (t >= d) ? sm[t - d] : 0;
        __syncthreads();
        sm[t] += u;
        __syncthreads();
    }
    if (t < nb) bsum[t] = sm[t] - v;   // exclusive
}

__global__ __launch_bounds__(256)
void scan_phase3(const int* __restrict__ cnt, const int* __restrict__ bsum,
                 int* __restrict__ off) {
    __shared__ int sm[256];
    int b = blockIdx.x, t = threadIdx.x;
    int base = b * 1024 + t * 4;
    int c0 = 0, c1 = 0, c2 = 0, c3 = 0;
    if (base + 3 < RN) {
        int4 v = *(const int4*)(cnt + base);
        c0 = v.x; c1 = v.y; c2 = v.z; c3 = v.w;
    } else {
        if (base + 0 < RN) c0 = cnt[base + 0];
        if (base + 1 < RN) c1 = cnt[base + 1];
        if (base + 2 < RN) c2 = cnt[base + 2];
        if (base + 3 < RN) c3 = cnt[base + 3];
    }
    int s = c0 + c1 + c2 + c3;
    sm[t] = s;
    __syncthreads();
    for (int d = 1; d < 256; d <<= 1) {
        int u = (t >= d) ? sm[t - d] : 0;
        __syncthreads();
        sm[t] += u;
        __syncthreads();
    }
    int pre = bsum[b] + sm[t] - s;
    if (base + 0 < RN) off[base + 0] = pre;
    if (base + 1 < RN) off[base + 1] = pre + c0;
    if (base + 2 < RN) off[base + 2] = pre + c0 + c1;
    if (base + 3 < RN) off[base + 3] = pre + c0 + c1 + c2;
}

// ---------------- bucket scan (1173 buckets, single block) ----------------
__global__ __launch_bounds__(256)
void bscan_kernel(const int* __restrict__ bcnt, int* __restrict__ bstart,
                  int* __restrict__ boff) {
    __shared__ int sm[256];
    int t = threadIdx.x;
    int loc[5];
    int s = 0;
    #pragma unroll
    for (int i = 0; i < 5; ++i) {
        int idx = t * 5 + i;
        int v = (idx < NBK) ? bcnt[idx] : 0;
        loc[i] = v; s += v;
    }
    sm[t] = s;
    __syncthreads();
    for (int d = 1; d < 256; d <<= 1) {
        int u = (t >= d) ? sm[t - d] : 0;
        __syncthreads();
        sm[t] += u;
        __syncthreads();
    }
    int run = sm[t] - s;   // exclusive prefix
    #pragma unroll
    for (int i = 0; i < 5; ++i) {
        int idx = t * 5 + i;
        if (idx < NBK) { bstart[idx] = run; boff[idx] = run; run += loc[i]; }
    }
}

// ------- phase A: block-aggregated bucket scatter (LDS hist + range reservation) -------
__global__ __launch_bounds__(256)
void bscatterA(const int* __restrict__ src, const int* __restrict__ dst,
               int* __restrict__ boff, unsigned* __restrict__ bpair) {
    __shared__ int hist[NBK];
    __shared__ int base[NBK];
    for (int i = threadIdx.x; i < NBK; i += 256) hist[i] = 0;
    __syncthreads();
    long ebase = (long)blockIdx.x * ECHUNK;
    for (int i = threadIdx.x; i < ECHUNK; i += 256) {
        long e = ebase + i;
        if (e < RE)
            atomicAdd(&hist[rel_of(e) * NTPR + (dst[e] >> 7)], 1);
    }
    __syncthreads();
    for (int i = threadIdx.x; i < NBK; i += 256) {
        int v = hist[i];
        base[i] = v ? atomicAdd(&boff[i], v) : 0;   // one reservation per (block,bucket)
    }
    __syncthreads();
    for (int i = threadIdx.x; i < ECHUNK; i += 256) {
        long e = ebase + i;
        if (e < RE) {
            int r = rel_of(e);
            int d = dst[e];
            int b = r * NTPR + (d >> 7);
            int pos = atomicAdd(&base[b], 1);       // LDS cursor bump
            bpair[pos] = ((unsigned)(d & 127) << 16) | (unsigned)src[e];
        }
    }
}

// ------- phase B: per-bucket local scatter, zero global atomics -------
__global__ __launch_bounds__(256)
void scatterB(const unsigned* __restrict__ bpair, const int* __restrict__ bstart,
              const int* __restrict__ bcnt, const int* __restrict__ off,
              int* __restrict__ csr) {
    __shared__ int nb[128], cur[128];
    int b = blockIdx.x;
    int r = b / NTPR, tile = b - r * NTPR;
    if (threadIdx.x < 128) {
        int nloc = tile * 128 + threadIdx.x;
        nb[threadIdx.x] = (nloc < NN) ? off[r * NN + nloc] : 0;
        cur[threadIdx.x] = 0;
    }
    __syncthreads();
    int start = bstart[b], end = start + bcnt[b];
    for (int i = start + threadIdx.x; i < end; i += 256) {
        unsigned p = bpair[i];
        int d = (int)(p >> 16);
        int rank = atomicAdd(&cur[d], 1);           // LDS only
        csr[nb[d] + rank] = (int)(p & 0xFFFFu);
    }
}

// ------- aggregation: wave per (r,node), 4-way ILP-unrolled bf16 gather -------
__global__ __launch_bounds__(256)
void gather_kernel(const short* __restrict__ featb,
                   const int* __restrict__ csr,
                   const int* __restrict__ off,   // START offsets (never mutated)
                   const int* __restrict__ cnt,
                   short* __restrict__ ssumb) {   // [R][N][F] <- bf16(feat + mean)
    int gid = blockIdx.x * blockDim.x + threadIdx.x;
    int w = gid >> 6, lane = gid & 63;
    if (w >= RN) return;
    int c = cnt[w];
    int start = off[w];
    int end = start + c;
    const int* f2 = (const int*)featb;
    float ax0 = 0.f, ay0 = 0.f, ax1 = 0.f, ay1 = 0.f;
    float ax2 = 0.f, ay2 = 0.f, ax3 = 0.f, ay3 = 0.f;
    int j = start;
    for (; j + 3 < end; j += 4) {
        int s0 = csr[j + 0];
        int s1 = csr[j + 1];
        int s2 = csr[j + 2];
        int s3 = csr[j + 3];
        int v0 = f2[(size_t)s0 * 64 + lane];
        int v1 = f2[(size_t)s1 * 64 + lane];
        int v2 = f2[(size_t)s2 * 64 + lane];
        int v3 = f2[(size_t)s3 * 64 + lane];
        ax0 += bs2f_lo(v0); ay0 += bs2f_hi(v0);
        ax1 += bs2f_lo(v1); ay1 += bs2f_hi(v1);
        ax2 += bs2f_lo(v2); ay2 += bs2f_hi(v2);
        ax3 += bs2f_lo(v3); ay3 += bs2f_hi(v3);
    }
    for (; j < end; ++j) {
        int s = csr[j];
        int v = f2[(size_t)s * 64 + lane];
        ax0 += bs2f_lo(v); ay0 += bs2f_hi(v);
    }
    float ax = (ax0 + ax1) + (ax2 + ax3);
    float ay = (ay0 + ay1) + (ay2 + ay3);
    float inv = 1.0f / fmaxf((float)c, 1.0f);
    int n = w % NN;
    int fv = f2[(size_t)n * 64 + lane];
    float hx = bs2f_lo(fv) + ax * inv;
    float hy = bs2f_hi(fv) + ay * inv;
    unsigned plo = (unsigned short)f2bs(hx);
    unsigned phi = (unsigned short)f2bs(hy);
    ((int*)ssumb)[(size_t)w * 64 + lane] = (int)((phi << 16) | plo);
}

// ---- fused MFMA transform: 1024-thr block, 16 waves, 16-node tile/wave, LDS weights ----
#define TW 16

__device__ __forceinline__ void mfma_layer(const bf16x8 A[4], const short* Wlds,
                                           int g8, int c, f32x4 acc[8]) {
    #pragma unroll
    for (int kk = 0; kk < 4; ++kk) {
        #pragma unroll
        for (int t = 0; t < 8; ++t) {
            int d = t * 16 + c;
            bf16x8 B = *(const bf16x8*)&Wlds[d * 128 + ((kk * 32 + g8) ^ ((d & 7) << 3))];
            acc[t] = __builtin_amdgcn_mfma_f32_16x16x32_bf16(A[kk], B, acc[t], 0, 0, 0);
        }
    }
}

template <bool RELU, bool BIAS>
__device__ __forceinline__ void ln_block(f32x4 acc[8], const float* bias,
                                         const float* gam, const float* bet, int c) {
    float s0 = 0, s1 = 0, s2 = 0, s3 = 0, p0 = 0, p1 = 0, p2 = 0, p3 = 0;
    #pragma unroll
    for (int t = 0; t < 8; ++t) {
        if (BIAS) {
            float bb = bias[t * 16 + c];
            acc[t][0] += bb; acc[t][1] += bb;
            acc[t][2] += bb; acc[t][3] += bb;
        }
        s0 += acc[t][0]; p0 += acc[t][0] * acc[t][0];
        s1 += acc[t][1]; p1 += acc[t][1] * acc[t][1];
        s2 += acc[t][2]; p2 += acc[t][2] * acc[t][2];
        s3 += acc[t][3]; p3 += acc[t][3] * acc[t][3];
    }
    #pragma unroll
    for (int m = 1; m < 16; m <<= 1) {
        s0 += __shfl_xor(s0, m); s1 += __shfl_xor(s1, m);
        s2 += __shfl_xor(s2, m); s3 += __shfl_xor(s3, m);
        p0 += __shfl_xor(p0, m); p1 += __shfl_xor(p1, m);
        p2 += __shfl_xor(p2, m); p3 += __shfl_xor(p3, m);
    }
    const float inv = 1.0f / 128.0f;
    float mu0 = s0 * inv, mu1 = s1 * inv, mu2 = s2 * inv, mu3 = s3 * inv;
    float r0 = rsqrtf(p0 * inv - mu0 * mu0 + EPSF);
    float r1 = rsqrtf(p1 * inv - mu1 * mu1 + EPSF);
    float r2 = rsqrtf(p2 * inv - mu2 * mu2 + EPSF);
    float r3 = rsqrtf(p3 * inv - mu3 * mu3 + EPSF);
    #pragma unroll
    for (int t = 0; t < 8; ++t) {
        float gg = gam[t * 16 + c], bb = bet[t * 16 + c];
        float v0 = (acc[t][0] - mu0) * r0 * gg + bb;
        float v1 = (acc[t][1] - mu1) * r1 * gg + bb;
        float v2 = (acc[t][2] - mu2) * r2 * gg + bb;
        float v3 = (acc[t][3] - mu3) * r3 * gg + bb;
        if (RELU) {
            v0 = fmaxf(v0, 0.f); v1 = fmaxf(v1, 0.f);
            v2 = fmaxf(v2, 0.f); v3 = fmaxf(v3, 0.f);
        }
        acc[t][0] = v0; acc[t][1] = v1;
        acc[t][2] = v2; acc[t][3] = v3;
    }
}

__device__ __forceinline__ void store_ht(const f32x4 acc[8], short* myht, int g, int c) {
    #pragma unroll
    for (int t = 0; t < 8; ++t) {
        int col = t * 16 + c;
        #pragma unroll
        for (int qq = 0; qq < 4; ++qq) {
            int row = g * 4 + qq;
            myht[row * 128 + (col ^ ((row & 7) << 3))] = f2bs(acc[t][qq]);
        }
    }
}

__device__ __forceinline__ void load_A(bf16x8 A[4], const short* myht, int g8, int c) {
    #pragma unroll
    for (int kk = 0; kk < 4; ++kk)
        A[kk] = *(const bf16x8*)&myht[c * 128 + ((kk * 32 + g8) ^ ((c & 7) << 3))];
}

__global__ __launch_bounds__(1024, 1)
void fused_transform(short* hbuf,                 // ssumb in, h (bf16) out, in-place
                     const float* __restrict__ W0, const float* __restrict__ b0,
                     const float* __restrict__ W1, const float* __restrict__ b1,
                     const float* __restrict__ ln_g, const float* __restrict__ ln_b,
                     const float* __restrict__ LN_g, const float* __restrict__ LN_b,
                     const float* __restrict__ Wa1, const float* __restrict__ Wa2,
                     float* __restrict__ evec) {
    __shared__ short W0t[FF * DD];        // 32 KiB, [d][k] bf16, XOR-swizzled
    __shared__ short W1t[DD * DD];        // 32 KiB
    __shared__ short Wa1t[AA * DD];       // 16 KiB
    __shared__ short ht[TW][16 * DD];     // 64 KiB (16 waves x 4 KiB)
    __shared__ float b0s[DD], b1s[DD], lgs[DD], lbs[DD], Lgs[DD], Lbs[DD], wa2s[AA];

    const int r = blockIdx.y;
    const int tid = threadIdx.x;

    for (int i = tid; i < FF * DD; i += 1024) {
        int k = i >> 7, d = i & 127;
        int idx = d * 128 + (k ^ ((d & 7) << 3));
        W0t[idx] = f2bs(W0[(size_t)r * FF * DD + i]);
        W1t[idx] = f2bs(W1[(size_t)r * DD * DD + i]);
    }
    for (int i = tid; i < DD * AA; i += 1024) {
        int k = i >> 6, a = i & 63;
        Wa1t[a * 128 + (k ^ ((a & 7) << 3))] = f2bs(Wa1[(size_t)r * DD * AA + i]);
    }
    if (tid < DD) {
        b0s[tid] = b0[r * DD + tid];
        b1s[tid] = b1[r * DD + tid];
        lgs[tid] = ln_g[r * DD + tid];
        lbs[tid] = ln_b[r * DD + tid];
        Lgs[tid] = LN_g[tid];
        Lbs[tid] = LN_b[tid];
    }
    if (tid < AA) wa2s[tid] = Wa2[r * AA + tid];
    __syncthreads();

    const int wv = tid >> 6, ln = tid & 63;
    const int g = ln >> 4, c = ln & 15;
    const int g8 = g * 8;
    short* myht = ht[wv];

    const int ntiles = NN / 16;                      // 3125 exactly
    for (int tile = blockIdx.x * TW + wv; tile < ntiles; tile += gridDim.x * TW) {
        const int nbase = tile * 16;

        // layer-1 A fragments straight from global (bf16 h = feat + mean)
        bf16x8 A1[4];
        {
            const short* sp = hbuf + ((size_t)r * NN + nbase + c) * FF;
            #pragma unroll
            for (int kk = 0; kk < 4; ++kk)
                A1[kk] = *(const bf16x8*)(sp + kk * 32 + g8);
        }

        f32x4 acc[8];
        #pragma unroll
        for (int t = 0; t < 8; ++t) acc[t] = (f32x4){0.f, 0.f, 0.f, 0.f};

        mfma_layer(A1, W0t, g8, c, acc);
        ln_block<true, true>(acc, b0s, lgs, lbs, c);
        store_ht(acc, myht, g, c);

        bf16x8 A2[4];
        load_A(A2, myht, g8, c);
        #pragma unroll
        for (int t = 0; t < 8; ++t) acc[t] = (f32x4){0.f, 0.f, 0.f, 0.f};
        mfma_layer(A2, W1t, g8, c, acc);
        ln_block<true, true>(acc, b1s, lgs, lbs, c);
        ln_block<false, false>(acc, nullptr, Lgs, Lbs, c);
        store_ht(acc, myht, g, c);

        // copy h tile LDS -> global, coalesced (16 rows x 256 B contiguous)
        {
            short* gout = hbuf + ((size_t)r * NN + nbase) * FF;
            #pragma unroll
            for (int cc = 0; cc < 4; ++cc) {
                int row = cc * 4 + g;
                int col0 = c * 8;
                bf16x8 v = *(const bf16x8*)&myht[row * 128 + (col0 ^ ((row & 7) << 3))];
                *(bf16x8*)&gout[row * FF + col0] = v;
            }
        }

        // semantic attention scores: e = tanh(h @ Wa1) . Wa2
        bf16x8 A3[4];
        load_A(A3, myht, g8, c);
        f32x4 accA[4];
        #pragma unroll
        for (int t = 0; t < 4; ++t) accA[t] = (f32x4){0.f, 0.f, 0.f, 0.f};
        #pragma unroll
        for (int kk = 0; kk < 4; ++kk)
            #pragma unroll
            for (int t = 0; t < 4; ++t) {
                int a_ = t * 16 + c;
                bf16x8 B = *(const bf16x8*)&Wa1t[a_ * 128 + ((kk * 32 + g8) ^ ((a_ & 7) << 3))];
                accA[t] = __builtin_amdgcn_mfma_f32_16x16x32_bf16(A3[kk], B, accA[t], 0, 0, 0);
            }
        {
            float e0 = 0, e1 = 0, e2 = 0, e3 = 0;
            #pragma unroll
            for (int t = 0; t < 4; ++t) {
                float w2v = wa2s[t * 16 + c];
                e0 += ftanh(accA[t][0]) * w2v;
                e1 += ftanh(accA[t][1]) * w2v;
                e2 += ftanh(accA[t][2]) * w2v;
                e3 += ftanh(accA[t][3]) * w2v;
            }
            #pragma unroll
            for (int m = 1; m < 16; m <<= 1) {
                e0 += __shfl_xor(e0, m); e1 += __shfl_xor(e1, m);
                e2 += __shfl_xor(e2, m); e3 += __shfl_xor(e3, m);
            }
            int nb = nbase + g * 4;
            if (c == 0) evec[(size_t)r * NN + nb + 0] = e0;
            if (c == 1) evec[(size_t)r * NN + nb + 1] = e1;
            if (c == 2) evec[(size_t)r * NN + nb + 2] = e2;
            if (c == 3) evec[(size_t)r * NN + nb + 3] = e3;
        }
    }
}

// ---------------- softmax over relations + weighted combine ----------------
__global__ __launch_bounds__(256)
void combine_kernel(const short* __restrict__ hfb,
                    const float* __restrict__ evec,
                    float* __restrict__ out) {
    int gid = blockIdx.x * blockDim.x + threadIdx.x;
    if (gid >= NN * 64) return;
    int n = gid >> 6, j = gid & 63;
    float e0 = evec[n], e1 = evec[NN + n], e2 = evec[2 * NN + n];
    float m = fmaxf(e0, fmaxf(e1, e2));
    float w0 = __expf(e0 - m), w1 = __expf(e1 - m), w2 = __expf(e2 - m);
    float inv = 1.0f / (w0 + w1 + w2);
    w0 *= inv; w1 *= inv; w2 *= inv;
    const int* h0 = (const int*)hfb + (size_t)n * 64;
    const int* h1 = (const int*)hfb + ((size_t)NN + n) * 64;
    const int* h2 = (const int*)hfb + ((size_t)2 * NN + n) * 64;
    int a = h0[j], b = h1[j], d = h2[j];
    float2 o;
    o.x = w0 * bs2f_lo(a) + w1 * bs2f_lo(b) + w2 * bs2f_lo(d);
    o.y = w0 * bs2f_hi(a) + w1 * bs2f_hi(b) + w2 * bs2f_hi(d);
    ((float2*)out)[(size_t)n * 64 + j] = o;
}

extern "C" void kernel_launch(void* const* d_in, const int* in_sizes, int n_in,
                              void* d_out, int out_size, void* d_ws, size_t ws_size,
                              hipStream_t stream) {
    const float* feat = (const float*)d_in[0];
    const int*   src  = (const int*)d_in[1];
    const int*   dst  = (const int*)d_in[2];
    const float* W0   = (const float*)d_in[3];
    const float* b0   = (const float*)d_in[4];
    const float* W1   = (const float*)d_in[5];
    const float* b1   = (const float*)d_in[6];
    const float* ln_g = (const float*)d_in[7];
    const float* ln_b = (const float*)d_in[8];
    const float* LN_g = (const float*)d_in[9];
    const float* LN_b = (const float*)d_in[10];
    const float* Wa1  = (const float*)d_in[11];
    const float* Wa2  = (const float*)d_in[12];
    float* out = (float*)d_out;

    // workspace layout
    short*    ssumb  = (short*)d_ws;                        // RN*FF bf16 (38.4 MB)
    short*    featb  = ssumb + (size_t)RN * FF;             // NN*FF bf16 (12.8 MB)
    int*      cnt    = (int*)(featb + (size_t)NN * FF);     // RN
    int*      off    = cnt + RN;                            // RN (start offsets)
    int*      csr    = off + RN;                            // RE
    float*    evec   = (float*)(csr + RE);                  // RN
    int*      bsum   = (int*)(evec + RN);                   // 256
    int*      bcnt   = bsum + 256;                          // NBK
    int*      bstart = bcnt + NBK;                          // NBK
    int*      boff   = bstart + NBK;                        // NBK
    unsigned* bpair  = (unsigned*)(boff + NBK);             // RE (9.6 MB)

    const int NB = (RN + 1023) / 1024;                      // 147

    feat2bf16<<<(NN * 16 + 255) / 256, 256, 0, stream>>>(feat, featb);
    hipMemsetAsync(cnt, 0, (size_t)RN * sizeof(int), stream);
    hipMemsetAsync(bcnt, 0, (size_t)NBK * sizeof(int), stream);
    count_kernel<<<NEBLK, 256, 0, stream>>>(dst, cnt, bcnt);
    scan_phase1<<<NB, 256, 0, stream>>>(cnt, bsum);
    scan_phase2<<<1, 256, 0, stream>>>(bsum, NB);
    scan_phase3<<<NB, 256, 0, stream>>>(cnt, bsum, off);
    bscan_kernel<<<1, 256, 0, stream>>>(bcnt, bstart, boff);
    bscatterA<<<NEBLK, 256, 0, stream>>>(src, dst, boff, bpair);
    scatterB<<<NBK, 256, 0, stream>>>(bpair, bstart, bcnt, off, csr);
    gather_kernel<<<(RN * 64 + 255) / 256, 256, 0, stream>>>(featb, csr, off, cnt, ssumb);

    fused_transform<<<dim3(85, RR), 1024, 0, stream>>>(
        ssumb, W0, b0, W1, b1, ln_g, ln_b, LN_g, LN_b, Wa1, Wa2, evec);
    combine_kernel<<<(NN * 64 + 255) / 256, 256, 0, stream>>>(ssumb, evec, out);
}

// Round 13
// 406.560 us; speedup vs baseline: 1.3125x; 1.1722x over previous
//
#include <hip/hip_runtime.h>

#define RR 3
#define NN 50000
#define EE 800000
#define FF 128
#define DD 128
#define AA 64
#define EPSF 1e-5f
#define RN (RR * NN)
#define RE (RR * EE)
#define NTPR ((NN + 127) / 128)     // 391 dst-tiles (128 nodes) per relation
#define NBK (RR * NTPR)             // 1173 buckets
#define ECHUNK 8192                 // edges per bucketing block
#define NEBLK ((RE + ECHUNK - 1) / ECHUNK)   // 293
#define NTILES (NN / 16)            // 3125 exact

typedef __attribute__((ext_vector_type(8))) short bf16x8;
typedef __attribute__((ext_vector_type(4))) float f32x4;

__device__ __forceinline__ short f2bs(float x) {
    union { float f; unsigned u; } v; v.f = x;
    unsigned rr = (v.u + 0x7fffu + ((v.u >> 16) & 1u)) >> 16;  // RNE
    return (short)(rr & 0xffffu);
}

__device__ __forceinline__ float bs2f_lo(int p) {
    union { unsigned u; float f; } v; v.u = (unsigned)p << 16; return v.f;
}
__device__ __forceinline__ float bs2f_hi(int p) {
    union { unsigned u; float f; } v; v.u = (unsigned)p & 0xffff0000u; return v.f;
}

__device__ __forceinline__ int rel_of(long e) {
    return (e >= 2L * EE) ? 2 : ((e >= (long)EE) ? 1 : 0);
}

__device__ __forceinline__ float ftanh(float x) {   // overflow-safe fast tanh
    float a = __expf(2.0f * fabsf(x));
    return copysignf(1.0f - 2.0f / (a + 1.0f), x);
}

// ---------------- feat -> bf16 ----------------
__global__ __launch_bounds__(256)
void feat2bf16(const float* __restrict__ feat, short* __restrict__ featb) {
    int gid = blockIdx.x * blockDim.x + threadIdx.x;
    if (gid >= NN * 16) return;
    f32x4 a = ((const f32x4*)feat)[2 * gid];
    f32x4 b = ((const f32x4*)feat)[2 * gid + 1];
    bf16x8 o;
    o[0] = f2bs(a.x); o[1] = f2bs(a.y); o[2] = f2bs(a.z); o[3] = f2bs(a.w);
    o[4] = f2bs(b.x); o[5] = f2bs(b.y); o[6] = f2bs(b.z); o[7] = f2bs(b.w);
    ((bf16x8*)featb)[gid] = o;
}

// ------- count: per-node degree (global) + bucket histogram (LDS-aggregated) -------
__global__ __launch_bounds__(256)
void count_kernel(const int* __restrict__ dst, int* __restrict__ cnt,
                  int* __restrict__ bcnt) {
    __shared__ int hist[NBK];
    for (int i = threadIdx.x; i < NBK; i += 256) hist[i] = 0;
    __syncthreads();
    long ebase = (long)blockIdx.x * ECHUNK;
    for (int i = threadIdx.x; i < ECHUNK; i += 256) {
        long e = ebase + i;
        if (e < RE) {
            int r = rel_of(e);
            int d = dst[e];
            atomicAdd(&cnt[r * NN + d], 1);
            atomicAdd(&hist[r * NTPR + (d >> 7)], 1);
        }
    }
    __syncthreads();
    for (int i = threadIdx.x; i < NBK; i += 256) {
        int v = hist[i];
        if (v) atomicAdd(&bcnt[i], v);   // no-return, spread
    }
}

// ---------------- node-offset scan (3-phase over RN) -> START offsets ----------------
__global__ __launch_bounds__(256)
void scan_phase1(const int* __restrict__ cnt, int* __restrict__ bsum) {
    __shared__ int sm[4];
    int b = blockIdx.x, t = threadIdx.x;
    int base = b * 1024 + t * 4;
    int s = 0;
    if (base + 3 < RN) {
        int4 v = *(const int4*)(cnt + base);
        s = v.x + v.y + v.z + v.w;
    } else {
        for (int i = 0; i < 4; ++i) if (base + i < RN) s += cnt[base + i];
    }
    #pragma unroll
    for (int m = 1; m < 64; m <<= 1) s += __shfl_xor(s, m);
    if ((t & 63) == 0) sm[t >> 6] = s;
    __syncthreads();
    if (t == 0) bsum[b] = sm[0] + sm[1] + sm[2] + sm[3];
}

__global__ __launch_bounds__(256)
void scan_phase2(int* __restrict__ bsum, int nb) {   // single block
    __shared__ int sm[256];
    int t = threadIdx.x;
    int v = (t < nb) ? bsum[t] : 0;
    sm[t] = v;
    __syncthreads();
    for (int d = 1; d < 256; d <<= 1) {
        int u = (t >= d) ? sm[t - d] : 0;
        __syncthreads();
        sm[t] += u;
        __syncthreads();
    }
    if (t < nb) bsum[t] = sm[t] - v;   // exclusive
}

__global__ __launch_bounds__(256)
void scan_phase3(const int* __restrict__ cnt, const int* __restrict__ bsum,
                 int* __restrict__ off) {
    __shared__ int sm[256];
    int b = blockIdx.x, t = threadIdx.x;
    int base = b * 1024 + t * 4;
    int c0 = 0, c1 = 0, c2 = 0, c3 = 0;
    if (base + 3 < RN) {
        int4 v = *(const int4*)(cnt + base);
        c0 = v.x; c1 = v.y; c2 = v.z; c3 = v.w;
    } else {
        if (base + 0 < RN) c0 = cnt[base + 0];
        if (base + 1 < RN) c1 = cnt[base + 1];
        if (base + 2 < RN) c2 = cnt[base + 2];
        if (base + 3 < RN) c3 = cnt[base + 3];
    }
    int s = c0 + c1 + c2 + c3;
    sm[t] = s;
    __syncthreads();
    for (int d = 1; d < 256; d <<= 1) {
        int u = (t >= d) ? sm[t - d] : 0;
        __syncthreads();
        sm[t] += u;
        __syncthreads();
    }
    int pre = bsum[b] + sm[t] - s;
    if (base + 0 < RN) off[base + 0] = pre;
    if (base + 1 < RN) off[base + 1] = pre + c0;
    if (base + 2 < RN) off[base + 2] = pre + c0 + c1;
    if (base + 3 < RN) off[base + 3] = pre + c0 + c1 + c2;
}

// ---------------- bucket scan (1173 buckets, single block) ----------------
__global__ __launch_bounds__(256)
void bscan_kernel(const int* __restrict__ bcnt, int* __restrict__ bstart,
                  int* __restrict__ boff) {
    __shared__ int sm[256];
    int t = threadIdx.x;
    int loc[5];
    int s = 0;
    #pragma unroll
    for (int i = 0; i < 5; ++i) {
        int idx = t * 5 + i;
        int v = (idx < NBK) ? bcnt[idx] : 0;
        loc[i] = v; s += v;
    }
    sm[t] = s;
    __syncthreads();
    for (int d = 1; d < 256; d <<= 1) {
        int u = (t >= d) ? sm[t - d] : 0;
        __syncthreads();
        sm[t] += u;
        __syncthreads();
    }
    int run = sm[t] - s;   // exclusive prefix
    #pragma unroll
    for (int i = 0; i < 5; ++i) {
        int idx = t * 5 + i;
        if (idx < NBK) { bstart[idx] = run; boff[idx] = run; run += loc[i]; }
    }
}

// ------- phase A: block-aggregated bucket scatter (LDS hist + range reservation) -------
__global__ __launch_bounds__(256)
void bscatterA(const int* __restrict__ src, const int* __restrict__ dst,
               int* __restrict__ boff, unsigned* __restrict__ bpair) {
    __shared__ int hist[NBK];
    __shared__ int base[NBK];
    for (int i = threadIdx.x; i < NBK; i += 256) hist[i] = 0;
    __syncthreads();
    long ebase = (long)blockIdx.x * ECHUNK;
    for (int i = threadIdx.x; i < ECHUNK; i += 256) {
        long e = ebase + i;
        if (e < RE)
            atomicAdd(&hist[rel_of(e) * NTPR + (dst[e] >> 7)], 1);
    }
    __syncthreads();
    for (int i = threadIdx.x; i < NBK; i += 256) {
        int v = hist[i];
        base[i] = v ? atomicAdd(&boff[i], v) : 0;   // one reservation per (block,bucket)
    }
    __syncthreads();
    for (int i = threadIdx.x; i < ECHUNK; i += 256) {
        long e = ebase + i;
        if (e < RE) {
            int r = rel_of(e);
            int d = dst[e];
            int b = r * NTPR + (d >> 7);
            int pos = atomicAdd(&base[b], 1);       // LDS cursor bump
            bpair[pos] = ((unsigned)(d & 127) << 16) | (unsigned)src[e];
        }
    }
}

// ------- phase B: per-bucket local scatter, zero global atomics -------
__global__ __launch_bounds__(256)
void scatterB(const unsigned* __restrict__ bpair, const int* __restrict__ bstart,
              const int* __restrict__ bcnt, const int* __restrict__ off,
              int* __restrict__ csr) {
    __shared__ int nb[128], cur[128];
    int b = blockIdx.x;
    int r = b / NTPR, tile = b - r * NTPR;
    if (threadIdx.x < 128) {
        int nloc = tile * 128 + threadIdx.x;
        nb[threadIdx.x] = (nloc < NN) ? off[r * NN + nloc] : 0;
        cur[threadIdx.x] = 0;
    }
    __syncthreads();
    int start = bstart[b], end = start + bcnt[b];
    for (int i = start + threadIdx.x; i < end; i += 256) {
        unsigned p = bpair[i];
        int d = (int)(p >> 16);
        int rank = atomicAdd(&cur[d], 1);           // LDS only
        csr[nb[d] + rank] = (int)(p & 0xFFFFu);
    }
}

// ------- aggregation: wave per (r,node), 8-way ILP-unrolled bf16 gather -------
__global__ __launch_bounds__(256)
void gather_kernel(const short* __restrict__ featb,
                   const int* __restrict__ csr,
                   const int* __restrict__ off,   // START offsets (never mutated)
                   const int* __restrict__ cnt,
                   short* __restrict__ ssumb) {   // [R][N][F] <- bf16(feat + mean)
    int gid = blockIdx.x * blockDim.x + threadIdx.x;
    int w = gid >> 6, lane = gid & 63;
    if (w >= RN) return;
    int c = cnt[w];
    int start = off[w];
    int end = start + c;
    const int* f2 = (const int*)featb;
    float ax0 = 0.f, ay0 = 0.f, ax1 = 0.f, ay1 = 0.f;
    float ax2 = 0.f, ay2 = 0.f, ax3 = 0.f, ay3 = 0.f;
    float ax4 = 0.f, ay4 = 0.f, ax5 = 0.f, ay5 = 0.f;
    float ax6 = 0.f, ay6 = 0.f, ax7 = 0.f, ay7 = 0.f;
    int j = start;
    for (; j + 7 < end; j += 8) {
        int s0 = csr[j + 0], s1 = csr[j + 1], s2 = csr[j + 2], s3 = csr[j + 3];
        int s4 = csr[j + 4], s5 = csr[j + 5], s6 = csr[j + 6], s7 = csr[j + 7];
        int v0 = f2[(size_t)s0 * 64 + lane];
        int v1 = f2[(size_t)s1 * 64 + lane];
        int v2 = f2[(size_t)s2 * 64 + lane];
        int v3 = f2[(size_t)s3 * 64 + lane];
        int v4 = f2[(size_t)s4 * 64 + lane];
        int v5 = f2[(size_t)s5 * 64 + lane];
        int v6 = f2[(size_t)s6 * 64 + lane];
        int v7 = f2[(size_t)s7 * 64 + lane];
        ax0 += bs2f_lo(v0); ay0 += bs2f_hi(v0);
        ax1 += bs2f_lo(v1); ay1 += bs2f_hi(v1);
        ax2 += bs2f_lo(v2); ay2 += bs2f_hi(v2);
        ax3 += bs2f_lo(v3); ay3 += bs2f_hi(v3);
        ax4 += bs2f_lo(v4); ay4 += bs2f_hi(v4);
        ax5 += bs2f_lo(v5); ay5 += bs2f_hi(v5);
        ax6 += bs2f_lo(v6); ay6 += bs2f_hi(v6);
        ax7 += bs2f_lo(v7); ay7 += bs2f_hi(v7);
    }
    for (; j + 3 < end; j += 4) {
        int s0 = csr[j + 0], s1 = csr[j + 1], s2 = csr[j + 2], s3 = csr[j + 3];
        int v0 = f2[(size_t)s0 * 64 + lane];
        int v1 = f2[(size_t)s1 * 64 + lane];
        int v2 = f2[(size_t)s2 * 64 + lane];
        int v3 = f2[(size_t)s3 * 64 + lane];
        ax0 += bs2f_lo(v0); ay0 += bs2f_hi(v0);
        ax1 += bs2f_lo(v1); ay1 += bs2f_hi(v1);
        ax2 += bs2f_lo(v2); ay2 += bs2f_hi(v2);
        ax3 += bs2f_lo(v3); ay3 += bs2f_hi(v3);
    }
    for (; j < end; ++j) {
        int s = csr[j];
        int v = f2[(size_t)s * 64 + lane];
        ax0 += bs2f_lo(v); ay0 += bs2f_hi(v);
    }
    float ax = ((ax0 + ax1) + (ax2 + ax3)) + ((ax4 + ax5) + (ax6 + ax7));
    float ay = ((ay0 + ay1) + (ay2 + ay3)) + ((ay4 + ay5) + (ay6 + ay7));
    float inv = 1.0f / fmaxf((float)c, 1.0f);
    int n = w % NN;
    int fv = f2[(size_t)n * 64 + lane];
    float hx = bs2f_lo(fv) + ax * inv;
    float hy = bs2f_hi(fv) + ay * inv;
    unsigned plo = (unsigned short)f2bs(hx);
    unsigned phi = (unsigned short)f2bs(hy);
    ((int*)ssumb)[(size_t)w * 64 + lane] = (int)((phi << 16) | plo);
}

// ======= split MFMA transform: 512-thr blocks, 8 waves, 16-node tile/wave =======
// Per-wave code identical to R12's proven fused_transform; only kernel boundaries moved.

__device__ __forceinline__ void mfma_layer(const bf16x8 A[4], const short* Wlds,
                                           int g8, int c, f32x4 acc[8]) {
    #pragma unroll
    for (int kk = 0; kk < 4; ++kk) {
        #pragma unroll
        for (int t = 0; t < 8; ++t) {
            int d = t * 16 + c;
            bf16x8 B = *(const bf16x8*)&Wlds[d * 128 + ((kk * 32 + g8) ^ ((d & 7) << 3))];
            acc[t] = __builtin_amdgcn_mfma_f32_16x16x32_bf16(A[kk], B, acc[t], 0, 0, 0);
        }
    }
}

template <bool RELU, bool BIAS>
__device__ __forceinline__ void ln_block(f32x4 acc[8], const float* bias,
                                         const float* gam, const float* bet, int c) {
    float s0 = 0, s1 = 0, s2 = 0, s3 = 0, p0 = 0, p1 = 0, p2 = 0, p3 = 0;
    #pragma unroll
    for (int t = 0; t < 8; ++t) {
        if (BIAS) {
            float bb = bias[t * 16 + c];
            acc[t][0] += bb; acc[t][1] += bb;
            acc[t][2] += bb; acc[t][3] += bb;
        }
        s0 += acc[t][0]; p0 += acc[t][0] * acc[t][0];
        s1 += acc[t][1]; p1 += acc[t][1] * acc[t][1];
        s2 += acc[t][2]; p2 += acc[t][2] * acc[t][2];
        s3 += acc[t][3]; p3 += acc[t][3] * acc[t][3];
    }
    #pragma unroll
    for (int m = 1; m < 16; m <<= 1) {
        s0 += __shfl_xor(s0, m); s1 += __shfl_xor(s1, m);
        s2 += __shfl_xor(s2, m); s3 += __shfl_xor(s3, m);
        p0 += __shfl_xor(p0, m); p1 += __shfl_xor(p1, m);
        p2 += __shfl_xor(p2, m); p3 += __shfl_xor(p3, m);
    }
    const float inv = 1.0f / 128.0f;
    float mu0 = s0 * inv, mu1 = s1 * inv, mu2 = s2 * inv, mu3 = s3 * inv;
    float r0 = rsqrtf(p0 * inv - mu0 * mu0 + EPSF);
    float r1 = rsqrtf(p1 * inv - mu1 * mu1 + EPSF);
    float r2 = rsqrtf(p2 * inv - mu2 * mu2 + EPSF);
    float r3 = rsqrtf(p3 * inv - mu3 * mu3 + EPSF);
    #pragma unroll
    for (int t = 0; t < 8; ++t) {
        float gg = gam[t * 16 + c], bb = bet[t * 16 + c];
        float v0 = (acc[t][0] - mu0) * r0 * gg + bb;
        float v1 = (acc[t][1] - mu1) * r1 * gg + bb;
        float v2 = (acc[t][2] - mu2) * r2 * gg + bb;
        float v3 = (acc[t][3] - mu3) * r3 * gg + bb;
        if (RELU) {
            v0 = fmaxf(v0, 0.f); v1 = fmaxf(v1, 0.f);
            v2 = fmaxf(v2, 0.f); v3 = fmaxf(v3, 0.f);
        }
        acc[t][0] = v0; acc[t][1] = v1;
        acc[t][2] = v2; acc[t][3] = v3;
    }
}

__device__ __forceinline__ void store_ht(const f32x4 acc[8], short* myht, int g, int c) {
    #pragma unroll
    for (int t = 0; t < 8; ++t) {
        int col = t * 16 + c;
        #pragma unroll
        for (int qq = 0; qq < 4; ++qq) {
            int row = g * 4 + qq;
            myht[row * 128 + (col ^ ((row & 7) << 3))] = f2bs(acc[t][qq]);
        }
    }
}

__device__ __forceinline__ void ht_to_global(const short* myht, short* gout, int g, int c) {
    #pragma unroll
    for (int cc = 0; cc < 4; ++cc) {
        int row = cc * 4 + g;
        int col0 = c * 8;
        bf16x8 v = *(const bf16x8*)&myht[row * 128 + (col0 ^ ((row & 7) << 3))];
        *(bf16x8*)&gout[row * FF + col0] = v;
    }
}

// layer 1: X1 = relu(LN(h @ W0 + b0)), in-place over hbuf
__global__ __launch_bounds__(512)
void fused_l1(short* hbuf,
              const float* __restrict__ W0, const float* __restrict__ b0,
              const float* __restrict__ ln_g, const float* __restrict__ ln_b) {
    __shared__ short W0t[FF * DD];        // 32 KiB
    __shared__ short ht[8][16 * DD];      // 32 KiB
    __shared__ float b0s[DD], lgs[DD], lbs[DD];

    const int r = blockIdx.y;
    const int tid = threadIdx.x;

    for (int i = tid; i < FF * DD; i += 512) {
        int k = i >> 7, d = i & 127;
        W0t[d * 128 + (k ^ ((d & 7) << 3))] = f2bs(W0[(size_t)r * FF * DD + i]);
    }
    if (tid < DD) {
        b0s[tid] = b0[r * DD + tid];
        lgs[tid] = ln_g[r * DD + tid];
        lbs[tid] = ln_b[r * DD + tid];
    }
    __syncthreads();

    const int wv = tid >> 6, ln = tid & 63;
    const int g = ln >> 4, c = ln & 15;
    const int g8 = g * 8;
    short* myht = ht[wv];

    for (int tile = blockIdx.x * 8 + wv; tile < NTILES; tile += gridDim.x * 8) {
        const int nbase = tile * 16;
        bf16x8 A[4];
        {
            const short* sp = hbuf + ((size_t)r * NN + nbase + c) * FF;
            #pragma unroll
            for (int kk = 0; kk < 4; ++kk)
                A[kk] = *(const bf16x8*)(sp + kk * 32 + g8);
        }
        f32x4 acc[8];
        #pragma unroll
        for (int t = 0; t < 8; ++t) acc[t] = (f32x4){0.f, 0.f, 0.f, 0.f};
        mfma_layer(A, W0t, g8, c, acc);
        ln_block<true, true>(acc, b0s, lgs, lbs, c);
        store_ht(acc, myht, g, c);
        ht_to_global(myht, hbuf + ((size_t)r * NN + nbase) * FF, g, c);
    }
}

// layer 2 + final LN: h = LN(relu(LN(X1 @ W1 + b1))), in-place over hbuf
__global__ __launch_bounds__(512)
void fused_l2(short* hbuf,
              const float* __restrict__ W1, const float* __restrict__ b1,
              const float* __restrict__ ln_g, const float* __restrict__ ln_b,
              const float* __restrict__ LN_g, const float* __restrict__ LN_b) {
    __shared__ short W1t[DD * DD];        // 32 KiB
    __shared__ short ht[8][16 * DD];      // 32 KiB
    __shared__ float b1s[DD], lgs[DD], lbs[DD], Lgs[DD], Lbs[DD];

    const int r = blockIdx.y;
    const int tid = threadIdx.x;

    for (int i = tid; i < DD * DD; i += 512) {
        int k = i >> 7, d = i & 127;
        W1t[d * 128 + (k ^ ((d & 7) << 3))] = f2bs(W1[(size_t)r * DD * DD + i]);
    }
    if (tid < DD) {
        b1s[tid] = b1[r * DD + tid];
        lgs[tid] = ln_g[r * DD + tid];
        lbs[tid] = ln_b[r * DD + tid];
        Lgs[tid] = LN_g[tid];
        Lbs[tid] = LN_b[tid];
    }
    __syncthreads();

    const int wv = tid >> 6, ln = tid & 63;
    const int g = ln >> 4, c = ln & 15;
    const int g8 = g * 8;
    short* myht = ht[wv];

    for (int tile = blockIdx.x * 8 + wv; tile < NTILES; tile += gridDim.x * 8) {
        const int nbase = tile * 16;
        bf16x8 A[4];
        {
            const short* sp = hbuf + ((size_t)r * NN + nbase + c) * FF;
            #pragma unroll
            for (int kk = 0; kk < 4; ++kk)
                A[kk] = *(const bf16x8*)(sp + kk * 32 + g8);
        }
        f32x4 acc[8];
        #pragma unroll
        for (int t = 0; t < 8; ++t) acc[t] = (f32x4){0.f, 0.f, 0.f, 0.f};
        mfma_layer(A, W1t, g8, c, acc);
        ln_block<true, true>(acc, b1s, lgs, lbs, c);
        ln_block<false, false>(acc, nullptr, Lgs, Lbs, c);
        store_ht(acc, myht, g, c);
        ht_to_global(myht, hbuf + ((size_t)r * NN + nbase) * FF, g, c);
    }
}

// ---------- attention scores: e = tanh(h @ Wa1) . Wa2 (R11's kernel, verbatim) ----------
__global__ __launch_bounds__(256)
void attn_score(const short* __restrict__ hbuf,
                const float* __restrict__ Wa1, const float* __restrict__ Wa2,
                float* __restrict__ evec) {
    __shared__ short Wa1t[RR][AA * DD];   // 48 KiB, [r][a][k] swizzled
    __shared__ float wa2s[RR][AA];

    const int tid = threadIdx.x;
    for (int i = tid; i < RR * DD * AA; i += 256) {
        int r2 = i >> 13;                  // / 8192
        int rem = i & 8191;
        int k = rem >> 6, a = rem & 63;
        Wa1t[r2][a * 128 + (k ^ ((a & 7) << 3))] = f2bs(Wa1[i]);
    }
    if (tid < RR * AA) wa2s[tid >> 6][tid & 63] = Wa2[tid];
    __syncthreads();

    const int wv = tid >> 6, ln = tid & 63;
    const int col = ln & 15, g = ln >> 4;
    const int g8 = g * 8, g4 = g * 4;

    for (int idx = blockIdx.x * 4 + wv; idx < RR * NTILES; idx += gridDim.x * 4) {
        int r = idx / NTILES;
        int tile = idx - r * NTILES;
        int nbase = tile * 16;
        const short* hrow = hbuf + ((size_t)r * NN + nbase + col) * FF;

        f32x4 acc[4];
        #pragma unroll
        for (int t = 0; t < 4; ++t) acc[t] = (f32x4){0.f, 0.f, 0.f, 0.f};
        #pragma unroll
        for (int kk = 0; kk < 4; ++kk) {
            bf16x8 Bh = *(const bf16x8*)(hrow + kk * 32 + g8);
            #pragma unroll
            for (int t = 0; t < 4; ++t) {
                int a_ = t * 16 + col;
                bf16x8 Wf = *(const bf16x8*)&Wa1t[r][a_ * 128 + ((kk * 32 + g8) ^ ((a_ & 7) << 3))];
                acc[t] = __builtin_amdgcn_mfma_f32_16x16x32_bf16(Wf, Bh, acc[t], 0, 0, 0);
            }
        }
        float e = 0.f;
        #pragma unroll
        for (int t = 0; t < 4; ++t) {
            f32x4 wv2 = *(const f32x4*)&wa2s[r][t * 16 + g4];
            e += ftanh(acc[t][0]) * wv2[0] + ftanh(acc[t][1]) * wv2[1]
               + ftanh(acc[t][2]) * wv2[2] + ftanh(acc[t][3]) * wv2[3];
        }
        e += __shfl_xor(e, 16);
        e += __shfl_xor(e, 32);
        if (ln < 16) evec[(size_t)r * NN + nbase + ln] = e;
    }
}

// ---------------- softmax over relations + weighted combine ----------------
__global__ __launch_bounds__(256)
void combine_kernel(const short* __restrict__ hfb,
                    const float* __restrict__ evec,
                    float* __restrict__ out) {
    int gid = blockIdx.x * blockDim.x + threadIdx.x;
    if (gid >= NN * 64) return;
    int n = gid >> 6, j = gid & 63;
    float e0 = evec[n], e1 = evec[NN + n], e2 = evec[2 * NN + n];
    float m = fmaxf(e0, fmaxf(e1, e2));
    float w0 = __expf(e0 - m), w1 = __expf(e1 - m), w2 = __expf(e2 - m);
    float inv = 1.0f / (w0 + w1 + w2);
    w0 *= inv; w1 *= inv; w2 *= inv;
    const int* h0 = (const int*)hfb + (size_t)n * 64;
    const int* h1 = (const int*)hfb + ((size_t)NN + n) * 64;
    const int* h2 = (const int*)hfb + ((size_t)2 * NN + n) * 64;
    int a = h0[j], b = h1[j], d = h2[j];
    float2 o;
    o.x = w0 * bs2f_lo(a) + w1 * bs2f_lo(b) + w2 * bs2f_lo(d);
    o.y = w0 * bs2f_hi(a) + w1 * bs2f_hi(b) + w2 * bs2f_hi(d);
    ((float2*)out)[(size_t)n * 64 + j] = o;
}

extern "C" void kernel_launch(void* const* d_in, const int* in_sizes, int n_in,
                              void* d_out, int out_size, void* d_ws, size_t ws_size,
                              hipStream_t stream) {
    const float* feat = (const float*)d_in[0];
    const int*   src  = (const int*)d_in[1];
    const int*   dst  = (const int*)d_in[2];
    const float* W0   = (const float*)d_in[3];
    const float* b0   = (const float*)d_in[4];
    const float* W1   = (const float*)d_in[5];
    const float* b1   = (const float*)d_in[6];
    const float* ln_g = (const float*)d_in[7];
    const float* ln_b = (const float*)d_in[8];
    const float* LN_g = (const float*)d_in[9];
    const float* LN_b = (const float*)d_in[10];
    const float* Wa1  = (const float*)d_in[11];
    const float* Wa2  = (const float*)d_in[12];
    float* out = (float*)d_out;

    // workspace layout
    short*    ssumb  = (short*)d_ws;                        // RN*FF bf16 (38.4 MB)
    short*    featb  = ssumb + (size_t)RN * FF;             // NN*FF bf16 (12.8 MB)
    int*      cnt    = (int*)(featb + (size_t)NN * FF);     // RN
    int*      off    = cnt + RN;                            // RN (start offsets)
    int*      csr    = off + RN;                            // RE
    float*    evec   = (float*)(csr + RE);                  // RN
    int*      bsum   = (int*)(evec + RN);                   // 256
    int*      bcnt   = bsum + 256;                          // NBK
    int*      bstart = bcnt + NBK;                          // NBK
    int*      boff   = bstart + NBK;                        // NBK
    unsigned* bpair  = (unsigned*)(boff + NBK);             // RE (9.6 MB)

    const int NB = (RN + 1023) / 1024;                      // 147

    feat2bf16<<<(NN * 16 + 255) / 256, 256, 0, stream>>>(feat, featb);
    hipMemsetAsync(cnt, 0, (size_t)RN * sizeof(int), stream);
    hipMemsetAsync(bcnt, 0, (size_t)NBK * sizeof(int), stream);
    count_kernel<<<NEBLK, 256, 0, stream>>>(dst, cnt, bcnt);
    scan_phase1<<<NB, 256, 0, stream>>>(cnt, bsum);
    scan_phase2<<<1, 256, 0, stream>>>(bsum, NB);
    scan_phase3<<<NB, 256, 0, stream>>>(cnt, bsum, off);
    bscan_kernel<<<1, 256, 0, stream>>>(bcnt, bstart, boff);
    bscatterA<<<NEBLK, 256, 0, stream>>>(src, dst, boff, bpair);
    scatterB<<<NBK, 256, 0, stream>>>(bpair, bstart, bcnt, off, csr);
    gather_kernel<<<(RN * 64 + 255) / 256, 256, 0, stream>>>(featb, csr, off, cnt, ssumb);

    const int GX = (NTILES + 7) / 8;                        // 391 blocks/relation
    fused_l1<<<dim3(GX, RR), 512, 0, stream>>>(ssumb, W0, b0, ln_g, ln_b);
    fused_l2<<<dim3(GX, RR), 512, 0, stream>>>(ssumb, W1, b1, ln_g, ln_b, LN_g, LN_b);
    attn_score<<<512, 256, 0, stream>>>(ssumb, Wa1, Wa2, evec);
    combine_kernel<<<(NN * 64 + 255) / 256, 256, 0, stream>>>(ssumb, evec, out);
}

// Round 14
// 312.436 us; speedup vs baseline: 1.7079x; 1.3013x over previous
//
#include <hip/hip_runtime.h>

#define RR 3
#define NN 50000
#define EE 800000
#define FF 128
#define DD 128
#define AA 64
#define EPSF 1e-5f
#define RN (RR * NN)
#define RE (RR * EE)
#define NTPR ((NN + 127) / 128)     // 391 dst-tiles (128 nodes) per relation
#define NBK (RR * NTPR)             // 1173 buckets
#define ECHUNK 8192                 // edges per bucketing block
#define NEBLK ((RE + ECHUNK - 1) / ECHUNK)   // 293
#define NTILES (NN / 16)            // 3125 exact

typedef __attribute__((ext_vector_type(8))) short bf16x8;
typedef __attribute__((ext_vector_type(4))) float f32x4;

__device__ __forceinline__ short f2bs(float x) {
    union { float f; unsigned u; } v; v.f = x;
    unsigned rr = (v.u + 0x7fffu + ((v.u >> 16) & 1u)) >> 16;  // RNE
    return (short)(rr & 0xffffu);
}

__device__ __forceinline__ float bs2f_lo(int p) {
    union { unsigned u; float f; } v; v.u = (unsigned)p << 16; return v.f;
}
__device__ __forceinline__ float bs2f_hi(int p) {
    union { unsigned u; float f; } v; v.u = (unsigned)p & 0xffff0000u; return v.f;
}

__device__ __forceinline__ int rel_of(long e) {
    return (e >= 2L * EE) ? 2 : ((e >= (long)EE) ? 1 : 0);
}

__device__ __forceinline__ float ftanh(float x) {   // overflow-safe fast tanh
    float a = __expf(2.0f * fabsf(x));
    return copysignf(1.0f - 2.0f / (a + 1.0f), x);
}

// ---------------- feat -> bf16 ----------------
__global__ __launch_bounds__(256)
void feat2bf16(const float* __restrict__ feat, short* __restrict__ featb) {
    int gid = blockIdx.x * blockDim.x + threadIdx.x;
    if (gid >= NN * 16) return;
    f32x4 a = ((const f32x4*)feat)[2 * gid];
    f32x4 b = ((const f32x4*)feat)[2 * gid + 1];
    bf16x8 o;
    o[0] = f2bs(a.x); o[1] = f2bs(a.y); o[2] = f2bs(a.z); o[3] = f2bs(a.w);
    o[4] = f2bs(b.x); o[5] = f2bs(b.y); o[6] = f2bs(b.z); o[7] = f2bs(b.w);
    ((bf16x8*)featb)[gid] = o;
}

// ------- count: bucket histogram only (LDS-aggregated, no per-node atomics) -------
__global__ __launch_bounds__(256)
void count_kernel(const int* __restrict__ dst, int* __restrict__ bcnt) {
    __shared__ int hist[NBK];
    for (int i = threadIdx.x; i < NBK; i += 256) hist[i] = 0;
    __syncthreads();
    long ebase = (long)blockIdx.x * ECHUNK;
    for (int i = threadIdx.x; i < ECHUNK; i += 256) {
        long e = ebase + i;
        if (e < RE)
            atomicAdd(&hist[rel_of(e) * NTPR + (dst[e] >> 7)], 1);
    }
    __syncthreads();
    for (int i = threadIdx.x; i < NBK; i += 256) {
        int v = hist[i];
        if (v) atomicAdd(&bcnt[i], v);   // no-return, spread
    }
}

// ---------------- bucket scan (1173 buckets, single block) ----------------
__global__ __launch_bounds__(256)
void bscan_kernel(const int* __restrict__ bcnt, int* __restrict__ bstart,
                  int* __restrict__ boff) {
    __shared__ int sm[256];
    int t = threadIdx.x;
    int loc[5];
    int s = 0;
    #pragma unroll
    for (int i = 0; i < 5; ++i) {
        int idx = t * 5 + i;
        int v = (idx < NBK) ? bcnt[idx] : 0;
        loc[i] = v; s += v;
    }
    sm[t] = s;
    __syncthreads();
    for (int d = 1; d < 256; d <<= 1) {
        int u = (t >= d) ? sm[t - d] : 0;
        __syncthreads();
        sm[t] += u;
        __syncthreads();
    }
    int run = sm[t] - s;   // exclusive prefix
    #pragma unroll
    for (int i = 0; i < 5; ++i) {
        int idx = t * 5 + i;
        if (idx < NBK) { bstart[idx] = run; boff[idx] = run; run += loc[i]; }
    }
}

// ------- phase A: block-aggregated bucket scatter (LDS hist + range reservation) -------
__global__ __launch_bounds__(256)
void bscatterA(const int* __restrict__ src, const int* __restrict__ dst,
               int* __restrict__ boff, unsigned* __restrict__ bpair) {
    __shared__ int hist[NBK];
    __shared__ int base[NBK];
    for (int i = threadIdx.x; i < NBK; i += 256) hist[i] = 0;
    __syncthreads();
    long ebase = (long)blockIdx.x * ECHUNK;
    for (int i = threadIdx.x; i < ECHUNK; i += 256) {
        long e = ebase + i;
        if (e < RE)
            atomicAdd(&hist[rel_of(e) * NTPR + (dst[e] >> 7)], 1);
    }
    __syncthreads();
    for (int i = threadIdx.x; i < NBK; i += 256) {
        int v = hist[i];
        base[i] = v ? atomicAdd(&boff[i], v) : 0;   // one reservation per (block,bucket)
    }
    __syncthreads();
    for (int i = threadIdx.x; i < ECHUNK; i += 256) {
        long e = ebase + i;
        if (e < RE) {
            int r = rel_of(e);
            int d = dst[e];
            int b = r * NTPR + (d >> 7);
            int pos = atomicAdd(&base[b], 1);       // LDS cursor bump
            bpair[pos] = ((unsigned)(d & 127) << 16) | (unsigned)src[e];
        }
    }
}

// ------- phase B: per-bucket scatter + derive per-node cnt/off (no global scan) -------
__global__ __launch_bounds__(256)
void scatterB(const unsigned* __restrict__ bpair, const int* __restrict__ bstart,
              const int* __restrict__ bcnt,
              int* __restrict__ off, int* __restrict__ cnt,
              int* __restrict__ csr) {
    __shared__ int hist[128];    // per-node count within bucket
    __shared__ int pre[128];     // inclusive prefix
    __shared__ int base[128];    // global start offset per node
    int b = blockIdx.x;
    int r = b / NTPR, tile = b - r * NTPR;
    const int t = threadIdx.x;
    if (t < 128) hist[t] = 0;
    __syncthreads();
    int start = bstart[b], end = start + bcnt[b];
    for (int i = start + t; i < end; i += 256)
        atomicAdd(&hist[bpair[i] >> 16], 1);
    __syncthreads();
    if (t < 128) pre[t] = hist[t];
    __syncthreads();
    for (int d = 1; d < 128; d <<= 1) {
        int v = (t < 128 && t >= d) ? pre[t - d] : 0;
        __syncthreads();
        if (t < 128) pre[t] += v;
        __syncthreads();
    }
    if (t < 128) {
        int excl = pre[t] - hist[t];
        base[t] = start + excl;
        int nloc = tile * 128 + t;
        if (nloc < NN) {
            off[r * NN + nloc] = start + excl;    // coalesced
            cnt[r * NN + nloc] = hist[t];         // coalesced
        }
        hist[t] = 0;                              // reuse as placement cursor
    }
    __syncthreads();
    for (int i = start + t; i < end; i += 256) {
        unsigned p = bpair[i];
        int d = (int)(p >> 16);
        int rank = atomicAdd(&hist[d], 1);        // LDS only
        csr[base[d] + rank] = (int)(p & 0xFFFFu);
    }
}

// ------- aggregation: wave per (r,node), 8-way ILP-unrolled bf16 gather -------
__global__ __launch_bounds__(256)
void gather_kernel(const short* __restrict__ featb,
                   const int* __restrict__ csr,
                   const int* __restrict__ off,   // START offsets (never mutated)
                   const int* __restrict__ cnt,
                   short* __restrict__ ssumb) {   // [R][N][F] <- bf16(feat + mean)
    int gid = blockIdx.x * blockDim.x + threadIdx.x;
    int w = gid >> 6, lane = gid & 63;
    if (w >= RN) return;
    int c = cnt[w];
    int start = off[w];
    int end = start + c;
    const int* f2 = (const int*)featb;
    float ax0 = 0.f, ay0 = 0.f, ax1 = 0.f, ay1 = 0.f;
    float ax2 = 0.f, ay2 = 0.f, ax3 = 0.f, ay3 = 0.f;
    float ax4 = 0.f, ay4 = 0.f, ax5 = 0.f, ay5 = 0.f;
    float ax6 = 0.f, ay6 = 0.f, ax7 = 0.f, ay7 = 0.f;
    int j = start;
    for (; j + 7 < end; j += 8) {
        int s0 = csr[j + 0], s1 = csr[j + 1], s2 = csr[j + 2], s3 = csr[j + 3];
        int s4 = csr[j + 4], s5 = csr[j + 5], s6 = csr[j + 6], s7 = csr[j + 7];
        int v0 = f2[(size_t)s0 * 64 + lane];
        int v1 = f2[(size_t)s1 * 64 + lane];
        int v2 = f2[(size_t)s2 * 64 + lane];
        int v3 = f2[(size_t)s3 * 64 + lane];
        int v4 = f2[(size_t)s4 * 64 + lane];
        int v5 = f2[(size_t)s5 * 64 + lane];
        int v6 = f2[(size_t)s6 * 64 + lane];
        int v7 = f2[(size_t)s7 * 64 + lane];
        ax0 += bs2f_lo(v0); ay0 += bs2f_hi(v0);
        ax1 += bs2f_lo(v1); ay1 += bs2f_hi(v1);
        ax2 += bs2f_lo(v2); ay2 += bs2f_hi(v2);
        ax3 += bs2f_lo(v3); ay3 += bs2f_hi(v3);
        ax4 += bs2f_lo(v4); ay4 += bs2f_hi(v4);
        ax5 += bs2f_lo(v5); ay5 += bs2f_hi(v5);
        ax6 += bs2f_lo(v6); ay6 += bs2f_hi(v6);
        ax7 += bs2f_lo(v7); ay7 += bs2f_hi(v7);
    }
    for (; j + 3 < end; j += 4) {
        int s0 = csr[j + 0], s1 = csr[j + 1], s2 = csr[j + 2], s3 = csr[j + 3];
        int v0 = f2[(size_t)s0 * 64 + lane];
        int v1 = f2[(size_t)s1 * 64 + lane];
        int v2 = f2[(size_t)s2 * 64 + lane];
        int v3 = f2[(size_t)s3 * 64 + lane];
        ax0 += bs2f_lo(v0); ay0 += bs2f_hi(v0);
        ax1 += bs2f_lo(v1); ay1 += bs2f_hi(v1);
        ax2 += bs2f_lo(v2); ay2 += bs2f_hi(v2);
        ax3 += bs2f_lo(v3); ay3 += bs2f_hi(v3);
    }
    for (; j < end; ++j) {
        int s = csr[j];
        int v = f2[(size_t)s * 64 + lane];
        ax0 += bs2f_lo(v); ay0 += bs2f_hi(v);
    }
    float ax = ((ax0 + ax1) + (ax2 + ax3)) + ((ax4 + ax5) + (ax6 + ax7));
    float ay = ((ay0 + ay1) + (ay2 + ay3)) + ((ay4 + ay5) + (ay6 + ay7));
    float inv = 1.0f / fmaxf((float)c, 1.0f);
    int n = w % NN;
    int fv = f2[(size_t)n * 64 + lane];
    float hx = bs2f_lo(fv) + ax * inv;
    float hy = bs2f_hi(fv) + ay * inv;
    unsigned plo = (unsigned short)f2bs(hx);
    unsigned phi = (unsigned short)f2bs(hy);
    ((int*)ssumb)[(size_t)w * 64 + lane] = (int)((phi << 16) | plo);
}

// ======= split MFMA transform: 512-thr blocks, 8 waves, 16-node tile/wave =======

__device__ __forceinline__ void mfma_layer(const bf16x8 A[4], const short* Wlds,
                                           int g8, int c, f32x4 acc[8]) {
    #pragma unroll
    for (int kk = 0; kk < 4; ++kk) {
        #pragma unroll
        for (int t = 0; t < 8; ++t) {
            int d = t * 16 + c;
            bf16x8 B = *(const bf16x8*)&Wlds[d * 128 + ((kk * 32 + g8) ^ ((d & 7) << 3))];
            acc[t] = __builtin_amdgcn_mfma_f32_16x16x32_bf16(A[kk], B, acc[t], 0, 0, 0);
        }
    }
}

template <bool RELU, bool BIAS>
__device__ __forceinline__ void ln_block(f32x4 acc[8], const float* bias,
                                         const float* gam, const float* bet, int c) {
    float s0 = 0, s1 = 0, s2 = 0, s3 = 0, p0 = 0, p1 = 0, p2 = 0, p3 = 0;
    #pragma unroll
    for (int t = 0; t < 8; ++t) {
        if (BIAS) {
            float bb = bias[t * 16 + c];
            acc[t][0] += bb; acc[t][1] += bb;
            acc[t][2] += bb; acc[t][3] += bb;
        }
        s0 += acc[t][0]; p0 += acc[t][0] * acc[t][0];
        s1 += acc[t][1]; p1 += acc[t][1] * acc[t][1];
        s2 += acc[t][2]; p2 += acc[t][2] * acc[t][2];
        s3 += acc[t][3]; p3 += acc[t][3] * acc[t][3];
    }
    #pragma unroll
    for (int m = 1; m < 16; m <<= 1) {
        s0 += __shfl_xor(s0, m); s1 += __shfl_xor(s1, m);
        s2 += __shfl_xor(s2, m); s3 += __shfl_xor(s3, m);
        p0 += __shfl_xor(p0, m); p1 += __shfl_xor(p1, m);
        p2 += __shfl_xor(p2, m); p3 += __shfl_xor(p3, m);
    }
    const float inv = 1.0f / 128.0f;
    float mu0 = s0 * inv, mu1 = s1 * inv, mu2 = s2 * inv, mu3 = s3 * inv;
    float r0 = rsqrtf(p0 * inv - mu0 * mu0 + EPSF);
    float r1 = rsqrtf(p1 * inv - mu1 * mu1 + EPSF);
    float r2 = rsqrtf(p2 * inv - mu2 * mu2 + EPSF);
    float r3 = rsqrtf(p3 * inv - mu3 * mu3 + EPSF);
    #pragma unroll
    for (int t = 0; t < 8; ++t) {
        float gg = gam[t * 16 + c], bb = bet[t * 16 + c];
        float v0 = (acc[t][0] - mu0) * r0 * gg + bb;
        float v1 = (acc[t][1] - mu1) * r1 * gg + bb;
        float v2 = (acc[t][2] - mu2) * r2 * gg + bb;
        float v3 = (acc[t][3] - mu3) * r3 * gg + bb;
        if (RELU) {
            v0 = fmaxf(v0, 0.f); v1 = fmaxf(v1, 0.f);
            v2 = fmaxf(v2, 0.f); v3 = fmaxf(v3, 0.f);
        }
        acc[t][0] = v0; acc[t][1] = v1;
        acc[t][2] = v2; acc[t][3] = v3;
    }
}

__device__ __forceinline__ void store_ht(const f32x4 acc[8], short* myht, int g, int c) {
    #pragma unroll
    for (int t = 0; t < 8; ++t) {
        int col = t * 16 + c;
        #pragma unroll
        for (int qq = 0; qq < 4; ++qq) {
            int row = g * 4 + qq;
            myht[row * 128 + (col ^ ((row & 7) << 3))] = f2bs(acc[t][qq]);
        }
    }
}

__device__ __forceinline__ void ht_to_global(const short* myht, short* gout, int g, int c) {
    #pragma unroll
    for (int cc = 0; cc < 4; ++cc) {
        int row = cc * 4 + g;
        int col0 = c * 8;
        bf16x8 v = *(const bf16x8*)&myht[row * 128 + (col0 ^ ((row & 7) << 3))];
        *(bf16x8*)&gout[row * FF + col0] = v;
    }
}

// layer 1: X1 = relu(LN(h @ W0 + b0)), in-place over hbuf
__global__ __launch_bounds__(512)
void fused_l1(short* hbuf,
              const float* __restrict__ W0, const float* __restrict__ b0,
              const float* __restrict__ ln_g, const float* __restrict__ ln_b) {
    __shared__ short W0t[FF * DD];        // 32 KiB
    __shared__ short ht[8][16 * DD];      // 32 KiB
    __shared__ float b0s[DD], lgs[DD], lbs[DD];

    const int r = blockIdx.y;
    const int tid = threadIdx.x;

    for (int i = tid; i < FF * DD; i += 512) {
        int k = i >> 7, d = i & 127;
        W0t[d * 128 + (k ^ ((d & 7) << 3))] = f2bs(W0[(size_t)r * FF * DD + i]);
    }
    if (tid < DD) {
        b0s[tid] = b0[r * DD + tid];
        lgs[tid] = ln_g[r * DD + tid];
        lbs[tid] = ln_b[r * DD + tid];
    }
    __syncthreads();

    const int wv = tid >> 6, ln = tid & 63;
    const int g = ln >> 4, c = ln & 15;
    const int g8 = g * 8;
    short* myht = ht[wv];

    for (int tile = blockIdx.x * 8 + wv; tile < NTILES; tile += gridDim.x * 8) {
        const int nbase = tile * 16;
        bf16x8 A[4];
        {
            const short* sp = hbuf + ((size_t)r * NN + nbase + c) * FF;
            #pragma unroll
            for (int kk = 0; kk < 4; ++kk)
                A[kk] = *(const bf16x8*)(sp + kk * 32 + g8);
        }
        f32x4 acc[8];
        #pragma unroll
        for (int t = 0; t < 8; ++t) acc[t] = (f32x4){0.f, 0.f, 0.f, 0.f};
        mfma_layer(A, W0t, g8, c, acc);
        ln_block<true, true>(acc, b0s, lgs, lbs, c);
        store_ht(acc, myht, g, c);
        ht_to_global(myht, hbuf + ((size_t)r * NN + nbase) * FF, g, c);
    }
}

// layer 2 + final LN: h = LN(relu(LN(X1 @ W1 + b1))), in-place over hbuf
__global__ __launch_bounds__(512)
void fused_l2(short* hbuf,
              const float* __restrict__ W1, const float* __restrict__ b1,
              const float* __restrict__ ln_g, const float* __restrict__ ln_b,
              const float* __restrict__ LN_g, const float* __restrict__ LN_b) {
    __shared__ short W1t[DD * DD];        // 32 KiB
    __shared__ short ht[8][16 * DD];      // 32 KiB
    __shared__ float b1s[DD], lgs[DD], lbs[DD], Lgs[DD], Lbs[DD];

    const int r = blockIdx.y;
    const int tid = threadIdx.x;

    for (int i = tid; i < DD * DD; i += 512) {
        int k = i >> 7, d = i & 127;
        W1t[d * 128 + (k ^ ((d & 7) << 3))] = f2bs(W1[(size_t)r * DD * DD + i]);
    }
    if (tid < DD) {
        b1s[tid] = b1[r * DD + tid];
        lgs[tid] = ln_g[r * DD + tid];
        lbs[tid] = ln_b[r * DD + tid];
        Lgs[tid] = LN_g[tid];
        Lbs[tid] = LN_b[tid];
    }
    __syncthreads();

    const int wv = tid >> 6, ln = tid & 63;
    const int g = ln >> 4, c = ln & 15;
    const int g8 = g * 8;
    short* myht = ht[wv];

    for (int tile = blockIdx.x * 8 + wv; tile < NTILES; tile += gridDim.x * 8) {
        const int nbase = tile * 16;
        bf16x8 A[4];
        {
            const short* sp = hbuf + ((size_t)r * NN + nbase + c) * FF;
            #pragma unroll
            for (int kk = 0; kk < 4; ++kk)
                A[kk] = *(const bf16x8*)(sp + kk * 32 + g8);
        }
        f32x4 acc[8];
        #pragma unroll
        for (int t = 0; t < 8; ++t) acc[t] = (f32x4){0.f, 0.f, 0.f, 0.f};
        mfma_layer(A, W1t, g8, c, acc);
        ln_block<true, true>(acc, b1s, lgs, lbs, c);
        ln_block<false, false>(acc, nullptr, Lgs, Lbs, c);
        store_ht(acc, myht, g, c);
        ht_to_global(myht, hbuf + ((size_t)r * NN + nbase) * FF, g, c);
    }
}

// ---------- attention scores: e = tanh(h @ Wa1) . Wa2 (transposed mfma) ----------
__global__ __launch_bounds__(256)
void attn_score(const short* __restrict__ hbuf,
                const float* __restrict__ Wa1, const float* __restrict__ Wa2,
                float* __restrict__ evec) {
    __shared__ short Wa1t[RR][AA * DD];   // 48 KiB, [r][a][k] swizzled
    __shared__ float wa2s[RR][AA];

    const int tid = threadIdx.x;
    for (int i = tid; i < RR * DD * AA; i += 256) {
        int r2 = i >> 13;                  // / 8192
        int rem = i & 8191;
        int k = rem >> 6, a = rem & 63;
        Wa1t[r2][a * 128 + (k ^ ((a & 7) << 3))] = f2bs(Wa1[i]);
    }
    if (tid < RR * AA) wa2s[tid >> 6][tid & 63] = Wa2[tid];
    __syncthreads();

    const int wv = tid >> 6, ln = tid & 63;
    const int col = ln & 15, g = ln >> 4;
    const int g8 = g * 8, g4 = g * 4;

    for (int idx = blockIdx.x * 4 + wv; idx < RR * NTILES; idx += gridDim.x * 4) {
        int r = idx / NTILES;
        int tile = idx - r * NTILES;
        int nbase = tile * 16;
        const short* hrow = hbuf + ((size_t)r * NN + nbase + col) * FF;

        f32x4 acc[4];
        #pragma unroll
        for (int t = 0; t < 4; ++t) acc[t] = (f32x4){0.f, 0.f, 0.f, 0.f};
        #pragma unroll
        for (int kk = 0; kk < 4; ++kk) {
            bf16x8 Bh = *(const bf16x8*)(hrow + kk * 32 + g8);
            #pragma unroll
            for (int t = 0; t < 4; ++t) {
                int a_ = t * 16 + col;
                bf16x8 Wf = *(const bf16x8*)&Wa1t[r][a_ * 128 + ((kk * 32 + g8) ^ ((a_ & 7) << 3))];
                acc[t] = __builtin_amdgcn_mfma_f32_16x16x32_bf16(Wf, Bh, acc[t], 0, 0, 0);
            }
        }
        float e = 0.f;
        #pragma unroll
        for (int t = 0; t < 4; ++t) {
            f32x4 wv2 = *(const f32x4*)&wa2s[r][t * 16 + g4];
            e += ftanh(acc[t][0]) * wv2[0] + ftanh(acc[t][1]) * wv2[1]
               + ftanh(acc[t][2]) * wv2[2] + ftanh(acc[t][3]) * wv2[3];
        }
        e += __shfl_xor(e, 16);
        e += __shfl_xor(e, 32);
        if (ln < 16) evec[(size_t)r * NN + nbase + ln] = e;
    }
}

// ---------------- softmax over relations + weighted combine ----------------
__global__ __launch_bounds__(256)
void combine_kernel(const short* __restrict__ hfb,
                    const float* __restrict__ evec,
                    float* __restrict__ out) {
    int gid = blockIdx.x * blockDim.x + threadIdx.x;
    if (gid >= NN * 64) return;
    int n = gid >> 6, j = gid & 63;
    float e0 = evec[n], e1 = evec[NN + n], e2 = evec[2 * NN + n];
    float m = fmaxf(e0, fmaxf(e1, e2));
    float w0 = __expf(e0 - m), w1 = __expf(e1 - m), w2 = __expf(e2 - m);
    float inv = 1.0f / (w0 + w1 + w2);
    w0 *= inv; w1 *= inv; w2 *= inv;
    const int* h0 = (const int*)hfb + (size_t)n * 64;
    const int* h1 = (const int*)hfb + ((size_t)NN + n) * 64;
    const int* h2 = (const int*)hfb + ((size_t)2 * NN + n) * 64;
    int a = h0[j], b = h1[j], d = h2[j];
    float2 o;
    o.x = w0 * bs2f_lo(a) + w1 * bs2f_lo(b) + w2 * bs2f_lo(d);
    o.y = w0 * bs2f_hi(a) + w1 * bs2f_hi(b) + w2 * bs2f_hi(d);
    ((float2*)out)[(size_t)n * 64 + j] = o;
}

extern "C" void kernel_launch(void* const* d_in, const int* in_sizes, int n_in,
                              void* d_out, int out_size, void* d_ws, size_t ws_size,
                              hipStream_t stream) {
    const float* feat = (const float*)d_in[0];
    const int*   src  = (const int*)d_in[1];
    const int*   dst  = (const int*)d_in[2];
    const float* W0   = (const float*)d_in[3];
    const float* b0   = (const float*)d_in[4];
    const float* W1   = (const float*)d_in[5];
    const float* b1   = (const float*)d_in[6];
    const float* ln_g = (const float*)d_in[7];
    const float* ln_b = (const float*)d_in[8];
    const float* LN_g = (const float*)d_in[9];
    const float* LN_b = (const float*)d_in[10];
    const float* Wa1  = (const float*)d_in[11];
    const float* Wa2  = (const float*)d_in[12];
    float* out = (float*)d_out;

    // workspace layout
    short*    ssumb  = (short*)d_ws;                        // RN*FF bf16 (38.4 MB)
    short*    featb  = ssumb + (size_t)RN * FF;             // NN*FF bf16 (12.8 MB)
    int*      cnt    = (int*)(featb + (size_t)NN * FF);     // RN (written by scatterB)
    int*      off    = cnt + RN;                            // RN (written by scatterB)
    int*      csr    = off + RN;                            // RE
    float*    evec   = (float*)(csr + RE);                  // RN
    int*      bcnt   = (int*)(evec + RN);                   // NBK
    int*      bstart = bcnt + NBK;                          // NBK
    int*      boff   = bstart + NBK;                        // NBK
    unsigned* bpair  = (unsigned*)(boff + NBK);             // RE (9.6 MB)

    feat2bf16<<<(NN * 16 + 255) / 256, 256, 0, stream>>>(feat, featb);
    hipMemsetAsync(bcnt, 0, (size_t)NBK * sizeof(int), stream);
    count_kernel<<<NEBLK, 256, 0, stream>>>(dst, bcnt);
    bscan_kernel<<<1, 256, 0, stream>>>(bcnt, bstart, boff);
    bscatterA<<<NEBLK, 256, 0, stream>>>(src, dst, boff, bpair);
    scatterB<<<NBK, 256, 0, stream>>>(bpair, bstart, bcnt, off, cnt, csr);
    gather_kernel<<<(RN * 64 + 255) / 256, 256, 0, stream>>>(featb, csr, off, cnt, ssumb);

    const int GX = (NTILES + 7) / 8;                        // 391 blocks/relation
    fused_l1<<<dim3(GX, RR), 512, 0, stream>>>(ssumb, W0, b0, ln_g, ln_b);
    fused_l2<<<dim3(GX, RR), 512, 0, stream>>>(ssumb, W1, b1, ln_g, ln_b, LN_g, LN_b);
    attn_score<<<512, 256, 0, stream>>>(ssumb, Wa1, Wa2, evec);
    combine_kernel<<<(NN * 64 + 255) / 256, 256, 0, stream>>>(ssumb, evec, out);
}